// Round 13
// baseline (127.395 us; speedup 1.0000x reference)
//
#include <hip/hip_runtime.h>

typedef __attribute__((ext_vector_type(4))) short short4v;
typedef __attribute__((ext_vector_type(8))) short short8v;
typedef __attribute__((ext_vector_type(4))) float float4v;
typedef __attribute__((ext_vector_type(4))) int int4v;

#define GLD_LDS16(gsrc, ldst)                                                             \
    __builtin_amdgcn_global_load_lds(                                                     \
        (const __attribute__((address_space(1))) void*)(gsrc),                            \
        (__attribute__((address_space(3))) void*)(ldst), 16, 0, 0)

__device__ __forceinline__ short f2bf(float f) {
    unsigned u = __builtin_bit_cast(unsigned, f);
    u += 0x7fffu + ((u >> 16) & 1u);
    return (short)(u >> 16);
}

// ---------------- x: fp32 -> bf16 (vectorized) ----------------
__global__ void k_cvt_x(const float* __restrict__ x, short* __restrict__ xb) {
    int i = blockIdx.x * blockDim.x + threadIdx.x;
    float4v v = ((const float4v*)x)[i];
    short4v o;
    o[0] = f2bf(v[0]); o[1] = f2bf(v[1]); o[2] = f2bf(v[2]); o[3] = f2bf(v[3]);
    ((short4v*)xb)[i] = o;
}

// ---------------- W[k][n] fp32 -> Wt[n][k] bf16 (LDS tile transpose) ----------------
__global__ void k_transpose(const float* __restrict__ W0, const float* __restrict__ W1,
                            const float* __restrict__ W2, const float* __restrict__ W3,
                            short* __restrict__ Wt) {
    const float* W = blockIdx.z == 0 ? W0 : blockIdx.z == 1 ? W1 : blockIdx.z == 2 ? W2 : W3;
    short* dst = Wt + (size_t)blockIdx.z * 1024 * 1024;
    __shared__ float tile[32][33];
    int x0 = blockIdx.x * 32, y0 = blockIdx.y * 32;
    int tx = threadIdx.x, ty = threadIdx.y;
#pragma unroll
    for (int j = 0; j < 4; j++) {
        int r = ty + j * 8;
        tile[r][tx] = W[(size_t)(y0 + r) * 1024 + x0 + tx];
    }
    __syncthreads();
#pragma unroll
    for (int j = 0; j < 4; j++) {
        int r = ty + j * 8;
        dst[(size_t)(x0 + r) * 1024 + y0 + tx] = f2bf(tile[tx][r]);
    }
}

// ---------------- merged QKV GEMM: 128x128 tile, BK=64, 8 waves, 2-phase dbuf --------
// z = 0 -> Q (exp2 scale), 1 -> K (both head-major bf16); 2 -> V via swapped MFMA
// operands -> V^T [B,H,Dh,S] with s-contiguous writes.
__launch_bounds__(512, 4)
__global__ void k_gemmQKV(const short* __restrict__ A, const short* __restrict__ Wtb,
                          short* __restrict__ Qb, short* __restrict__ Kb,
                          short* __restrict__ Vtb) {
    __shared__ short As[2][128][64];
    __shared__ short Bs[2][128][64];
    int t = threadIdx.x;
    int l = t & 63, w = t >> 6;
    int wm = w >> 2, wn = w & 3;
    int lr = l & 15, lg = l >> 4;
    int m0 = blockIdx.x * 128, n0 = blockIdx.y * 128;
    int which = blockIdx.z;
    const short* Bp = Wtb + ((size_t)which << 20);

    int srow = l >> 3;
    int sg = (l & 7) ^ srow;
    const short* Ab0 = A + (size_t)(m0 + w * 8 + srow) * 1024 + sg * 8;
    const short* Ab1 = Ab0 + 64 * 1024;
    const short* Bb0 = Bp + (size_t)(n0 + w * 8 + srow) * 1024 + sg * 8;
    const short* Bb1 = Bb0 + 64 * 1024;

    float4v acc[4][2] = {};

#define STAGE(bb, k0)                                   \
    do {                                                \
        GLD_LDS16(Ab0 + (k0), &As[bb][w * 8][0]);       \
        GLD_LDS16(Ab1 + (k0), &As[bb][64 + w * 8][0]);  \
        GLD_LDS16(Bb0 + (k0), &Bs[bb][w * 8][0]);       \
        GLD_LDS16(Bb1 + (k0), &Bs[bb][64 + w * 8][0]);  \
    } while (0)

    STAGE(0, 0);
    __syncthreads();
    int cur = 0;

    if (which == 2) {                        // block-uniform branch: V (swapped)
        for (int kt = 0; kt < 16; kt++) {
            if (kt + 1 < 16) STAGE(cur ^ 1, (kt + 1) * 64);
#pragma unroll
            for (int ks = 0; ks < 2; ks++) {
                short8v af[4], bfv[2];
                int hh = ks * 4 + lg;
                int sw = ((hh ^ (lr & 7)) * 8);
#pragma unroll
                for (int fm = 0; fm < 4; fm++)
                    af[fm] = *(const short8v*)&As[cur][wm * 64 + fm * 16 + lr][sw];
#pragma unroll
                for (int fn = 0; fn < 2; fn++)
                    bfv[fn] = *(const short8v*)&Bs[cur][wn * 32 + fn * 16 + lr][sw];
                __builtin_amdgcn_s_setprio(1);
#pragma unroll
                for (int fm = 0; fm < 4; fm++)
#pragma unroll
                    for (int fn = 0; fn < 2; fn++)
                        acc[fm][fn] = __builtin_amdgcn_mfma_f32_16x16x32_bf16(bfv[fn], af[fm], acc[fm][fn], 0, 0, 0);
                __builtin_amdgcn_s_setprio(0);
            }
            __syncthreads();
            cur ^= 1;
        }
    } else {
        for (int kt = 0; kt < 16; kt++) {
            if (kt + 1 < 16) STAGE(cur ^ 1, (kt + 1) * 64);
#pragma unroll
            for (int ks = 0; ks < 2; ks++) {
                short8v af[4], bfv[2];
                int hh = ks * 4 + lg;
                int sw = ((hh ^ (lr & 7)) * 8);
#pragma unroll
                for (int fm = 0; fm < 4; fm++)
                    af[fm] = *(const short8v*)&As[cur][wm * 64 + fm * 16 + lr][sw];
#pragma unroll
                for (int fn = 0; fn < 2; fn++)
                    bfv[fn] = *(const short8v*)&Bs[cur][wn * 32 + fn * 16 + lr][sw];
                __builtin_amdgcn_s_setprio(1);
#pragma unroll
                for (int fm = 0; fm < 4; fm++)
#pragma unroll
                    for (int fn = 0; fn < 2; fn++)
                        acc[fm][fn] = __builtin_amdgcn_mfma_f32_16x16x32_bf16(af[fm], bfv[fn], acc[fm][fn], 0, 0, 0);
                __builtin_amdgcn_s_setprio(0);
            }
            __syncthreads();
            cur ^= 1;
        }
    }
#undef STAGE

    if (which < 2) {
        short* out = (which == 0) ? Qb : Kb;
        float scale = (which == 0) ? 0.125f * 1.44269504088896f : 1.0f;
#pragma unroll
        for (int fm = 0; fm < 4; fm++)
#pragma unroll
            for (int fn = 0; fn < 2; fn++)
#pragma unroll
                for (int r = 0; r < 4; r++) {
                    int m = m0 + wm * 64 + fm * 16 + lg * 4 + r;
                    int n = n0 + wn * 32 + fn * 16 + lr;
                    float v = acc[fm][fn][r] * scale;
                    int b = m >> 11, s = m & 2047, h = n >> 6, dh = n & 63;
                    out[(((size_t)(b * 16 + h)) * 2048 + s) * 64 + dh] = f2bf(v);
                }
    } else {
#pragma unroll
        for (int fm = 0; fm < 4; fm++)
#pragma unroll
            for (int fn = 0; fn < 2; fn++)
#pragma unroll
                for (int r = 0; r < 4; r++) {
                    int n = n0 + wn * 32 + fn * 16 + lg * 4 + r;
                    int m = m0 + wm * 64 + fm * 16 + lr;
                    int b = m >> 11, s = m & 2047, h = n >> 6, dh = n & 63;
                    Vtb[(((size_t)(b * 16 + h)) * 64 + dh) * 2048 + s] = f2bf(acc[fm][fn][r]);
                }
    }
}

// ---------------- O-projection GEMM (fp32 out) ----------------
__launch_bounds__(512, 4)
__global__ void k_gemmO(const short* __restrict__ A, const short* __restrict__ Bt,
                        float* __restrict__ outF) {
    __shared__ short As[2][128][64];
    __shared__ short Bs[2][128][64];
    int t = threadIdx.x;
    int l = t & 63, w = t >> 6;
    int wm = w >> 2, wn = w & 3;
    int lr = l & 15, lg = l >> 4;
    int m0 = blockIdx.x * 128, n0 = blockIdx.y * 128;

    int srow = l >> 3;
    int sg = (l & 7) ^ srow;
    const short* Ab0 = A + (size_t)(m0 + w * 8 + srow) * 1024 + sg * 8;
    const short* Ab1 = Ab0 + 64 * 1024;
    const short* Bb0 = Bt + (size_t)(n0 + w * 8 + srow) * 1024 + sg * 8;
    const short* Bb1 = Bb0 + 64 * 1024;

    float4v acc[4][2] = {};

#define STAGE(bb, k0)                                   \
    do {                                                \
        GLD_LDS16(Ab0 + (k0), &As[bb][w * 8][0]);       \
        GLD_LDS16(Ab1 + (k0), &As[bb][64 + w * 8][0]);  \
        GLD_LDS16(Bb0 + (k0), &Bs[bb][w * 8][0]);       \
        GLD_LDS16(Bb1 + (k0), &Bs[bb][64 + w * 8][0]);  \
    } while (0)

    STAGE(0, 0);
    __syncthreads();
    int cur = 0;

    for (int kt = 0; kt < 16; kt++) {
        if (kt + 1 < 16) STAGE(cur ^ 1, (kt + 1) * 64);
#pragma unroll
        for (int ks = 0; ks < 2; ks++) {
            short8v af[4], bfv[2];
            int hh = ks * 4 + lg;
            int sw = ((hh ^ (lr & 7)) * 8);
#pragma unroll
            for (int fm = 0; fm < 4; fm++)
                af[fm] = *(const short8v*)&As[cur][wm * 64 + fm * 16 + lr][sw];
#pragma unroll
            for (int fn = 0; fn < 2; fn++)
                bfv[fn] = *(const short8v*)&Bs[cur][wn * 32 + fn * 16 + lr][sw];
            __builtin_amdgcn_s_setprio(1);
#pragma unroll
            for (int fm = 0; fm < 4; fm++)
#pragma unroll
                for (int fn = 0; fn < 2; fn++)
                    acc[fm][fn] = __builtin_amdgcn_mfma_f32_16x16x32_bf16(af[fm], bfv[fn], acc[fm][fn], 0, 0, 0);
            __builtin_amdgcn_s_setprio(0);
        }
        __syncthreads();
        cur ^= 1;
    }
#undef STAGE

#pragma unroll
    for (int fm = 0; fm < 4; fm++)
#pragma unroll
        for (int fn = 0; fn < 2; fn++)
#pragma unroll
            for (int r = 0; r < 4; r++) {
                int m = m0 + wm * 64 + fm * 16 + lg * 4 + r;
                int n = n0 + wn * 32 + fn * 16 + lr;
                outF[(size_t)m * 1024 + n] = acc[fm][fn][r];
            }
}

// ---------------- causal flash attention v12: 4-stream balanced all-resident ----
// 1024 blocks x 2 waves; wave owns 32 q-rows (2 sub-tiles) of one 64-row tile.
// Tile map: L<512 -> 31-(L>>5) [heavy 32..17 chunks]; L>=512 -> (L-512)>>5
// [light 1..16]. Round-robin dispatch gives each CU 4 blocks summing 66 chunks.
// 40KB LDS -> 4 blocks/CU = 8 waves/CU. Swizzled K/V/P, 0 bank conflicts.
__launch_bounds__(128, 4)
__global__ void k_attn(const short* __restrict__ Qb, const short* __restrict__ Kb,
                       const short* __restrict__ Vtb, short* __restrict__ Ob) {
    __shared__ short K_lds[2][64][64];
    __shared__ short V_lds[2][64][64];
    __shared__ short p_lds[2][2][16][64];
    int t = threadIdx.x;
    int l = t & 63, w = t >> 6;          // 2 waves
    int lr = l & 15, lg = l >> 4;

    int L = blockIdx.x;                  // 0..1023
    int bh = L & 31;                     // L%8 = bh%8 -> XCD affinity
    int g = (L >> 5) & 15;
    int tile = (L < 512) ? (31 - g) : g;
    int nch = tile + 1;

    const short* Qp = Qb + (size_t)bh * 2048 * 64;
    const short* Kp = Kb + (size_t)bh * 2048 * 64;
    const short* Vp = Vtb + (size_t)bh * 64 * 2048;

    auto stage = [&](int bb, int kv0) {
#pragma unroll
        for (int i = 0; i < 4; i++) {
            int s = t + i * 128;
            int row = s >> 3, cg = s & 7;
            int cs = (cg ^ (row & 7)) * 8;
            GLD_LDS16(&Kp[(size_t)(kv0 + row) * 64 + cs], (short*)K_lds[bb] + (size_t)s * 8);
            GLD_LDS16(&Vp[(size_t)row * 2048 + kv0 + cs], (short*)V_lds[bb] + (size_t)s * 8);
        }
    };

    stage(0, 0);

    int q0a = tile * 64 + w * 32;
    int q0b = q0a + 16;
    short8v qf0a = *(const short8v*)&Qp[(size_t)(q0a + lr) * 64 + lg * 8];
    short8v qf1a = *(const short8v*)&Qp[(size_t)(q0a + lr) * 64 + 32 + lg * 8];
    short8v qf0b = *(const short8v*)&Qp[(size_t)(q0b + lr) * 64 + lg * 8];
    short8v qf1b = *(const short8v*)&Qp[(size_t)(q0b + lr) * 64 + 32 + lg * 8];

    float4v oa[4] = {}, ob[4] = {};
    float mra[4] = {-3e38f, -3e38f, -3e38f, -3e38f};
    float mrb[4] = {-3e38f, -3e38f, -3e38f, -3e38f};
    float lsa[4] = {0.f, 0.f, 0.f, 0.f};
    float lsb[4] = {0.f, 0.f, 0.f, 0.f};
    int cur = 0;
    int b = bh >> 4, h = bh & 15;

    auto softmax_store = [&](float4v (&s)[4], float (&mr)[4], float (&ls)[4],
                             float4v (&o)[4], int X) {
        float mx[4];
#pragma unroll
        for (int r = 0; r < 4; r++)
            mx[r] = fmaxf(fmaxf(s[0][r], s[1][r]), fmaxf(s[2][r], s[3][r]));
        float worst = fmaxf(fmaxf(mx[0] - mr[0], mx[1] - mr[1]),
                            fmaxf(mx[2] - mr[2], mx[3] - mr[3]));
        if (!__all(worst <= 8.f)) {
#pragma unroll
            for (int r = 0; r < 4; r++) {
                float m_ = mx[r];
                m_ = fmaxf(m_, __shfl_xor(m_, 1));
                m_ = fmaxf(m_, __shfl_xor(m_, 2));
                m_ = fmaxf(m_, __shfl_xor(m_, 4));
                m_ = fmaxf(m_, __shfl_xor(m_, 8));
                float mnew = fmaxf(mr[r], m_);
                float sc = __builtin_amdgcn_exp2f(mr[r] - mnew);
                mr[r] = mnew;
                ls[r] *= sc;
                o[0][r] *= sc; o[1][r] *= sc; o[2][r] *= sc; o[3][r] *= sc;
            }
        }
        int bg = lr >> 3, co = lr & 7;
#pragma unroll
        for (int r = 0; r < 4; r++) {
            int row = 4 * lg + r, rx = row & 7;
            float e0 = __builtin_amdgcn_exp2f(s[0][r] - mr[r]);
            float e1 = __builtin_amdgcn_exp2f(s[1][r] - mr[r]);
            float e2 = __builtin_amdgcn_exp2f(s[2][r] - mr[r]);
            float e3 = __builtin_amdgcn_exp2f(s[3][r] - mr[r]);
            ls[r] += (e0 + e1) + (e2 + e3);
            p_lds[w][X][row][((bg    ) ^ rx) * 8 + co] = f2bf(e0);
            p_lds[w][X][row][((bg + 2) ^ rx) * 8 + co] = f2bf(e1);
            p_lds[w][X][row][((bg + 4) ^ rx) * 8 + co] = f2bf(e2);
            p_lds[w][X][row][((bg + 6) ^ rx) * 8 + co] = f2bf(e3);
        }
    };

    __syncthreads();   // prologue stage drained

    for (int ci = 0; ci < nch; ci++) {
        int kv0 = ci * 64;

        if (ci + 1 < nch) stage(cur ^ 1, (ci + 1) * 64);

        const short* Kf = (const short*)K_lds[cur];
        float4v sa[4] = {}, sb[4] = {};
        __builtin_amdgcn_s_setprio(1);
#pragma unroll
        for (int t4 = 0; t4 < 4; t4++) {
            int krow = t4 * 16 + lr;
            int sw = (krow & 7);
            short8v kfa = *(const short8v*)&Kf[krow * 64 + ((lg ^ sw) * 8)];
            short8v kfb = *(const short8v*)&Kf[krow * 64 + (((lg ^ 4) ^ sw) * 8)];
            sa[t4] = __builtin_amdgcn_mfma_f32_16x16x32_bf16(qf0a, kfa, sa[t4], 0, 0, 0);
            sa[t4] = __builtin_amdgcn_mfma_f32_16x16x32_bf16(qf1a, kfb, sa[t4], 0, 0, 0);
            sb[t4] = __builtin_amdgcn_mfma_f32_16x16x32_bf16(qf0b, kfa, sb[t4], 0, 0, 0);
            sb[t4] = __builtin_amdgcn_mfma_f32_16x16x32_bf16(qf1b, kfb, sb[t4], 0, 0, 0);
        }
        __builtin_amdgcn_s_setprio(0);

        if (kv0 + 63 > q0a) {
#pragma unroll
            for (int t4 = 0; t4 < 4; t4++)
#pragma unroll
                for (int r = 0; r < 4; r++)
                    if (kv0 + t4 * 16 + lr > q0a + lg * 4 + r) sa[t4][r] = -3e38f;
        }
        if (kv0 + 63 > q0b) {
#pragma unroll
            for (int t4 = 0; t4 < 4; t4++)
#pragma unroll
                for (int r = 0; r < 4; r++)
                    if (kv0 + t4 * 16 + lr > q0b + lg * 4 + r) sb[t4][r] = -3e38f;
        }

        softmax_store(sa, mra, lsa, oa, 0);
        softmax_store(sb, mrb, lsb, ob, 1);

        int prx = lr & 7;
        short8v pa0 = *(const short8v*)&p_lds[w][0][lr][8 * (lg ^ prx)];
        short8v pa1 = *(const short8v*)&p_lds[w][0][lr][8 * ((4 + lg) ^ prx)];
        short8v pb0 = *(const short8v*)&p_lds[w][1][lr][8 * (lg ^ prx)];
        short8v pb1 = *(const short8v*)&p_lds[w][1][lr][8 * ((4 + lg) ^ prx)];

        const short* Vf = (const short*)V_lds[cur];
        __builtin_amdgcn_s_setprio(1);
#pragma unroll
        for (int dt = 0; dt < 4; dt++) {
            int vrow = dt * 16 + lr;
            int sw = (vrow & 7);
            short8v vfa = *(const short8v*)&Vf[vrow * 64 + ((lg ^ sw) * 8)];
            short8v vfb = *(const short8v*)&Vf[vrow * 64 + (((lg ^ 4) ^ sw) * 8)];
            oa[dt] = __builtin_amdgcn_mfma_f32_16x16x32_bf16(pa0, vfa, oa[dt], 0, 0, 0);
            oa[dt] = __builtin_amdgcn_mfma_f32_16x16x32_bf16(pa1, vfb, oa[dt], 0, 0, 0);
            ob[dt] = __builtin_amdgcn_mfma_f32_16x16x32_bf16(pb0, vfa, ob[dt], 0, 0, 0);
            ob[dt] = __builtin_amdgcn_mfma_f32_16x16x32_bf16(pb1, vfb, ob[dt], 0, 0, 0);
        }
        __builtin_amdgcn_s_setprio(0);

        __syncthreads();   // buffer flip: all reads of cur done + staging drained
        cur ^= 1;
    }

    // ---- finalize both sub-tiles ----
    float inva[4], invb[4];
#pragma unroll
    for (int r = 0; r < 4; r++) {
        float va = lsa[r], vb = lsb[r];
        va += __shfl_xor(va, 1); va += __shfl_xor(va, 2);
        va += __shfl_xor(va, 4); va += __shfl_xor(va, 8);
        vb += __shfl_xor(vb, 1); vb += __shfl_xor(vb, 2);
        vb += __shfl_xor(vb, 4); vb += __shfl_xor(vb, 8);
        inva[r] = 1.0f / va;
        invb[r] = 1.0f / vb;
    }
#pragma unroll
    for (int dt = 0; dt < 4; dt++)
#pragma unroll
        for (int r = 0; r < 4; r++) {
            int qa = q0a + lg * 4 + r;
            int qb = q0b + lg * 4 + r;
            Ob[((size_t)(b * 2048 + qa)) * 1024 + h * 64 + dt * 16 + lr] = f2bf(oa[dt][r] * inva[r]);
            Ob[((size_t)(b * 2048 + qb)) * 1024 + h * 64 + dt * 16 + lr] = f2bf(ob[dt][r] * invb[r]);
        }
}

extern "C" void kernel_launch(void* const* d_in, const int* in_sizes, int n_in,
                              void* d_out, int out_size, void* d_ws, size_t ws_size,
                              hipStream_t stream) {
    const float* x  = (const float*)d_in[0];
    const float* Wq = (const float*)d_in[1];
    const float* Wk = (const float*)d_in[2];
    const float* Wv = (const float*)d_in[3];
    const float* Wo = (const float*)d_in[4];
    float* out = (float*)d_out;

    char* ws = (char*)d_ws;
    short* xb  = (short*)(ws);                 // [4096][1024] bf16       8 MB
    short* Wtb = (short*)(ws + 8388608);       // 4 x [1024 n][1024 k]    8 MB
    short* Qb  = (short*)(ws + 16777216);      // [B,H,S,Dh] (pre-scaled) 8 MB
    short* Kb  = (short*)(ws + 25165824);      // [B,H,S,Dh]              8 MB
    short* Vtb = (short*)(ws + 33554432);      // [B,H,Dh,S]              8 MB
    short* Ob  = (short*)(ws + 41943040);      // [B,S,D] bf16            8 MB

    k_cvt_x<<<4096, 256, 0, stream>>>(x, xb);
    k_transpose<<<dim3(32, 32, 4), dim3(32, 8), 0, stream>>>(Wq, Wk, Wv, Wo, Wtb);
    k_gemmQKV<<<dim3(32, 8, 3), 512, 0, stream>>>(xb, Wtb, Qb, Kb, Vtb);
    k_attn<<<1024, 128, 0, stream>>>(Qb, Kb, Vtb, Ob);
    k_gemmO<<<dim3(32, 8), 512, 0, stream>>>(Ob, Wtb + 3 * 1048576, out);
}

// Round 14
// 115.380 us; speedup vs baseline: 1.1041x; 1.1041x over previous
//
#include <hip/hip_runtime.h>

typedef __attribute__((ext_vector_type(4))) short short4v;
typedef __attribute__((ext_vector_type(8))) short short8v;
typedef __attribute__((ext_vector_type(4))) float float4v;
typedef __attribute__((ext_vector_type(4))) int int4v;

#define GLD_LDS16(gsrc, ldst)                                                             \
    __builtin_amdgcn_global_load_lds(                                                     \
        (const __attribute__((address_space(1))) void*)(gsrc),                            \
        (__attribute__((address_space(3))) void*)(ldst), 16, 0, 0)

__device__ __forceinline__ short f2bf(float f) {
    unsigned u = __builtin_bit_cast(unsigned, f);
    u += 0x7fffu + ((u >> 16) & 1u);
    return (short)(u >> 16);
}

// ---------------- x: fp32 -> bf16 (vectorized) ----------------
__global__ void k_cvt_x(const float* __restrict__ x, short* __restrict__ xb) {
    int i = blockIdx.x * blockDim.x + threadIdx.x;
    float4v v = ((const float4v*)x)[i];
    short4v o;
    o[0] = f2bf(v[0]); o[1] = f2bf(v[1]); o[2] = f2bf(v[2]); o[3] = f2bf(v[3]);
    ((short4v*)xb)[i] = o;
}

// ---------------- W[k][n] fp32 -> Wt[n][k] bf16 (LDS tile transpose) ----------------
__global__ void k_transpose(const float* __restrict__ W0, const float* __restrict__ W1,
                            const float* __restrict__ W2, const float* __restrict__ W3,
                            short* __restrict__ Wt) {
    const float* W = blockIdx.z == 0 ? W0 : blockIdx.z == 1 ? W1 : blockIdx.z == 2 ? W2 : W3;
    short* dst = Wt + (size_t)blockIdx.z * 1024 * 1024;
    __shared__ float tile[32][33];
    int x0 = blockIdx.x * 32, y0 = blockIdx.y * 32;
    int tx = threadIdx.x, ty = threadIdx.y;
#pragma unroll
    for (int j = 0; j < 4; j++) {
        int r = ty + j * 8;
        tile[r][tx] = W[(size_t)(y0 + r) * 1024 + x0 + tx];
    }
    __syncthreads();
#pragma unroll
    for (int j = 0; j < 4; j++) {
        int r = ty + j * 8;
        dst[(size_t)(x0 + r) * 1024 + y0 + tx] = f2bf(tile[tx][r]);
    }
}

// ---------------- merged QKV GEMM: 128x128 tile, BK=64, 8 waves, 2-phase dbuf --------
// z = 0 -> Q (exp2 scale), 1 -> K (head-major bf16); 2 -> V via swapped MFMA
// operands -> V^T [B,H,Dh,S] with s-contiguous writes.
__launch_bounds__(512, 4)
__global__ void k_gemmQKV(const short* __restrict__ A, const short* __restrict__ Wtb,
                          short* __restrict__ Qb, short* __restrict__ Kb,
                          short* __restrict__ Vtb) {
    __shared__ short As[2][128][64];
    __shared__ short Bs[2][128][64];
    int t = threadIdx.x;
    int l = t & 63, w = t >> 6;
    int wm = w >> 2, wn = w & 3;
    int lr = l & 15, lg = l >> 4;
    int m0 = blockIdx.x * 128, n0 = blockIdx.y * 128;
    int which = blockIdx.z;
    const short* Bp = Wtb + ((size_t)which << 20);

    int srow = l >> 3;
    int sg = (l & 7) ^ srow;
    const short* Ab0 = A + (size_t)(m0 + w * 8 + srow) * 1024 + sg * 8;
    const short* Ab1 = Ab0 + 64 * 1024;
    const short* Bb0 = Bp + (size_t)(n0 + w * 8 + srow) * 1024 + sg * 8;
    const short* Bb1 = Bb0 + 64 * 1024;

    float4v acc[4][2] = {};

#define STAGE(bb, k0)                                   \
    do {                                                \
        GLD_LDS16(Ab0 + (k0), &As[bb][w * 8][0]);       \
        GLD_LDS16(Ab1 + (k0), &As[bb][64 + w * 8][0]);  \
        GLD_LDS16(Bb0 + (k0), &Bs[bb][w * 8][0]);       \
        GLD_LDS16(Bb1 + (k0), &Bs[bb][64 + w * 8][0]);  \
    } while (0)

    STAGE(0, 0);
    __syncthreads();
    int cur = 0;

    if (which == 2) {                        // block-uniform branch: V (swapped)
        for (int kt = 0; kt < 16; kt++) {
            if (kt + 1 < 16) STAGE(cur ^ 1, (kt + 1) * 64);
#pragma unroll
            for (int ks = 0; ks < 2; ks++) {
                short8v af[4], bfv[2];
                int hh = ks * 4 + lg;
                int sw = ((hh ^ (lr & 7)) * 8);
#pragma unroll
                for (int fm = 0; fm < 4; fm++)
                    af[fm] = *(const short8v*)&As[cur][wm * 64 + fm * 16 + lr][sw];
#pragma unroll
                for (int fn = 0; fn < 2; fn++)
                    bfv[fn] = *(const short8v*)&Bs[cur][wn * 32 + fn * 16 + lr][sw];
                __builtin_amdgcn_s_setprio(1);
#pragma unroll
                for (int fm = 0; fm < 4; fm++)
#pragma unroll
                    for (int fn = 0; fn < 2; fn++)
                        acc[fm][fn] = __builtin_amdgcn_mfma_f32_16x16x32_bf16(bfv[fn], af[fm], acc[fm][fn], 0, 0, 0);
                __builtin_amdgcn_s_setprio(0);
            }
            __syncthreads();
            cur ^= 1;
        }
    } else {
        for (int kt = 0; kt < 16; kt++) {
            if (kt + 1 < 16) STAGE(cur ^ 1, (kt + 1) * 64);
#pragma unroll
            for (int ks = 0; ks < 2; ks++) {
                short8v af[4], bfv[2];
                int hh = ks * 4 + lg;
                int sw = ((hh ^ (lr & 7)) * 8);
#pragma unroll
                for (int fm = 0; fm < 4; fm++)
                    af[fm] = *(const short8v*)&As[cur][wm * 64 + fm * 16 + lr][sw];
#pragma unroll
                for (int fn = 0; fn < 2; fn++)
                    bfv[fn] = *(const short8v*)&Bs[cur][wn * 32 + fn * 16 + lr][sw];
                __builtin_amdgcn_s_setprio(1);
#pragma unroll
                for (int fm = 0; fm < 4; fm++)
#pragma unroll
                    for (int fn = 0; fn < 2; fn++)
                        acc[fm][fn] = __builtin_amdgcn_mfma_f32_16x16x32_bf16(af[fm], bfv[fn], acc[fm][fn], 0, 0, 0);
                __builtin_amdgcn_s_setprio(0);
            }
            __syncthreads();
            cur ^= 1;
        }
    }
#undef STAGE

    if (which < 2) {
        short* out = (which == 0) ? Qb : Kb;
        float scale = (which == 0) ? 0.125f * 1.44269504088896f : 1.0f;
#pragma unroll
        for (int fm = 0; fm < 4; fm++)
#pragma unroll
            for (int fn = 0; fn < 2; fn++)
#pragma unroll
                for (int r = 0; r < 4; r++) {
                    int m = m0 + wm * 64 + fm * 16 + lg * 4 + r;
                    int n = n0 + wn * 32 + fn * 16 + lr;
                    float v = acc[fm][fn][r] * scale;
                    int b = m >> 11, s = m & 2047, h = n >> 6, dh = n & 63;
                    out[(((size_t)(b * 16 + h)) * 2048 + s) * 64 + dh] = f2bf(v);
                }
    } else {
#pragma unroll
        for (int fm = 0; fm < 4; fm++)
#pragma unroll
            for (int fn = 0; fn < 2; fn++)
#pragma unroll
                for (int r = 0; r < 4; r++) {
                    int n = n0 + wn * 32 + fn * 16 + lg * 4 + r;
                    int m = m0 + wm * 64 + fm * 16 + lr;
                    int b = m >> 11, s = m & 2047, h = n >> 6, dh = n & 63;
                    Vtb[(((size_t)(b * 16 + h)) * 64 + dh) * 2048 + s] = f2bf(acc[fm][fn][r]);
                }
    }
}

// ---------------- O-projection GEMM (fp32 out) ----------------
__launch_bounds__(512, 4)
__global__ void k_gemmO(const short* __restrict__ A, const short* __restrict__ Bt,
                        float* __restrict__ outF) {
    __shared__ short As[2][128][64];
    __shared__ short Bs[2][128][64];
    int t = threadIdx.x;
    int l = t & 63, w = t >> 6;
    int wm = w >> 2, wn = w & 3;
    int lr = l & 15, lg = l >> 4;
    int m0 = blockIdx.x * 128, n0 = blockIdx.y * 128;

    int srow = l >> 3;
    int sg = (l & 7) ^ srow;
    const short* Ab0 = A + (size_t)(m0 + w * 8 + srow) * 1024 + sg * 8;
    const short* Ab1 = Ab0 + 64 * 1024;
    const short* Bb0 = Bt + (size_t)(n0 + w * 8 + srow) * 1024 + sg * 8;
    const short* Bb1 = Bb0 + 64 * 1024;

    float4v acc[4][2] = {};

#define STAGE(bb, k0)                                   \
    do {                                                \
        GLD_LDS16(Ab0 + (k0), &As[bb][w * 8][0]);       \
        GLD_LDS16(Ab1 + (k0), &As[bb][64 + w * 8][0]);  \
        GLD_LDS16(Bb0 + (k0), &Bs[bb][w * 8][0]);       \
        GLD_LDS16(Bb1 + (k0), &Bs[bb][64 + w * 8][0]);  \
    } while (0)

    STAGE(0, 0);
    __syncthreads();
    int cur = 0;

    for (int kt = 0; kt < 16; kt++) {
        if (kt + 1 < 16) STAGE(cur ^ 1, (kt + 1) * 64);
#pragma unroll
        for (int ks = 0; ks < 2; ks++) {
            short8v af[4], bfv[2];
            int hh = ks * 4 + lg;
            int sw = ((hh ^ (lr & 7)) * 8);
#pragma unroll
            for (int fm = 0; fm < 4; fm++)
                af[fm] = *(const short8v*)&As[cur][wm * 64 + fm * 16 + lr][sw];
#pragma unroll
            for (int fn = 0; fn < 2; fn++)
                bfv[fn] = *(const short8v*)&Bs[cur][wn * 32 + fn * 16 + lr][sw];
            __builtin_amdgcn_s_setprio(1);
#pragma unroll
            for (int fm = 0; fm < 4; fm++)
#pragma unroll
                for (int fn = 0; fn < 2; fn++)
                    acc[fm][fn] = __builtin_amdgcn_mfma_f32_16x16x32_bf16(af[fm], bfv[fn], acc[fm][fn], 0, 0, 0);
            __builtin_amdgcn_s_setprio(0);
        }
        __syncthreads();
        cur ^= 1;
    }
#undef STAGE

#pragma unroll
    for (int fm = 0; fm < 4; fm++)
#pragma unroll
        for (int fn = 0; fn < 2; fn++)
#pragma unroll
            for (int r = 0; r < 4; r++) {
                int m = m0 + wm * 64 + fm * 16 + lg * 4 + r;
                int n = n0 + wn * 32 + fn * 16 + lr;
                outF[(size_t)m * 1024 + n] = acc[fm][fn][r];
            }
}

// ---------------- causal flash attention v13: stripe-paired + CU-sum-balanced ----
// R11 inner loop unchanged. p remap: g = L>>5; p = (g<8) ? g : 23-g, so blocks
// L=c (heavy, nch 25..32) and L=c+256 (light, nch 17..24) sum to 49 periods on
// every CU under round-robin placement. bh = L&31 keeps XCD affinity.
__launch_bounds__(256, 2)
__global__ void k_attn(const short* __restrict__ Qb, const short* __restrict__ Kb,
                       const short* __restrict__ Vtb, short* __restrict__ Ob) {
    __shared__ short K_lds[2][64][64];
    __shared__ short V_lds[2][64][64];
    __shared__ short p_lds[4][2][16][64];
    int t = threadIdx.x;
    int l = t & 63, w = t >> 6;
    int lr = l & 15, lg = l >> 4;

    int L = blockIdx.x;                      // 0..511
    int bh = L & 31;                         // L%8 = bh%8 -> XCD affinity
    int g = L >> 5;                          // 0..15
    int p = (g < 8) ? g : 23 - g;            // heavy first; CU pair sums constant
    int nch = 32 - p;                        // staged chunks (covers hi tile)

    const short* Qp = Qb + (size_t)bh * 2048 * 64;
    const short* Kp = Kb + (size_t)bh * 2048 * 64;
    const short* Vp = Vtb + (size_t)bh * 64 * 2048;

    auto stage = [&](int bb, int kv0) {
#pragma unroll
        for (int i = 0; i < 2; i++) {
            int s = t + i * 256;
            int row = s >> 3, cg = s & 7;
            int cs = (cg ^ (row & 7)) * 8;
            GLD_LDS16(&Kp[(size_t)(kv0 + row) * 64 + cs], (short*)K_lds[bb] + (size_t)s * 8);
            GLD_LDS16(&Vp[(size_t)row * 2048 + kv0 + cs], (short*)V_lds[bb] + (size_t)s * 8);
        }
    };

    stage(0, 0);

    int q0a = (31 - p) * 64 + w * 16;        // sub-tile A rows (hi tile)
    int q0b = p * 64 + w * 16;               // sub-tile B rows (lo tile)
    short8v qf0a = *(const short8v*)&Qp[(size_t)(q0a + lr) * 64 + lg * 8];
    short8v qf1a = *(const short8v*)&Qp[(size_t)(q0a + lr) * 64 + 32 + lg * 8];
    short8v qf0b = *(const short8v*)&Qp[(size_t)(q0b + lr) * 64 + lg * 8];
    short8v qf1b = *(const short8v*)&Qp[(size_t)(q0b + lr) * 64 + 32 + lg * 8];

    float4v oa[4] = {}, ob[4] = {};
    float mra[4] = {-3e38f, -3e38f, -3e38f, -3e38f};
    float mrb[4] = {-3e38f, -3e38f, -3e38f, -3e38f};
    float lsa[4] = {0.f, 0.f, 0.f, 0.f};
    float lsb[4] = {0.f, 0.f, 0.f, 0.f};
    int cur = 0;
    int b = bh >> 4, h = bh & 15;

    auto softmax_store = [&](float4v (&s)[4], float (&mr)[4], float (&ls)[4],
                             float4v (&o)[4], int X) {
        float mx[4];
#pragma unroll
        for (int r = 0; r < 4; r++)
            mx[r] = fmaxf(fmaxf(s[0][r], s[1][r]), fmaxf(s[2][r], s[3][r]));
        float worst = fmaxf(fmaxf(mx[0] - mr[0], mx[1] - mr[1]),
                            fmaxf(mx[2] - mr[2], mx[3] - mr[3]));
        if (!__all(worst <= 8.f)) {
#pragma unroll
            for (int r = 0; r < 4; r++) {
                float m_ = mx[r];
                m_ = fmaxf(m_, __shfl_xor(m_, 1));
                m_ = fmaxf(m_, __shfl_xor(m_, 2));
                m_ = fmaxf(m_, __shfl_xor(m_, 4));
                m_ = fmaxf(m_, __shfl_xor(m_, 8));
                float mnew = fmaxf(mr[r], m_);
                float sc = __builtin_amdgcn_exp2f(mr[r] - mnew);
                mr[r] = mnew;
                ls[r] *= sc;
                o[0][r] *= sc; o[1][r] *= sc; o[2][r] *= sc; o[3][r] *= sc;
            }
        }
        int bg = lr >> 3, co = lr & 7;
#pragma unroll
        for (int r = 0; r < 4; r++) {
            int row = 4 * lg + r, rx = row & 7;
            float e0 = __builtin_amdgcn_exp2f(s[0][r] - mr[r]);
            float e1 = __builtin_amdgcn_exp2f(s[1][r] - mr[r]);
            float e2 = __builtin_amdgcn_exp2f(s[2][r] - mr[r]);
            float e3 = __builtin_amdgcn_exp2f(s[3][r] - mr[r]);
            ls[r] += (e0 + e1) + (e2 + e3);
            p_lds[w][X][row][((bg    ) ^ rx) * 8 + co] = f2bf(e0);
            p_lds[w][X][row][((bg + 2) ^ rx) * 8 + co] = f2bf(e1);
            p_lds[w][X][row][((bg + 4) ^ rx) * 8 + co] = f2bf(e2);
            p_lds[w][X][row][((bg + 6) ^ rx) * 8 + co] = f2bf(e3);
        }
    };

    __syncthreads();   // prologue stage drained

    for (int ci = 0; ci < nch; ci++) {
        int kv0 = ci * 64;
        bool dual = (ci <= p);               // block-uniform: B sub-tile active

        if (ci + 1 < nch) stage(cur ^ 1, (ci + 1) * 64);

        const short* Kf = (const short*)K_lds[cur];
        float4v sa[4] = {}, sb[4] = {};
        __builtin_amdgcn_s_setprio(1);
#pragma unroll
        for (int t4 = 0; t4 < 4; t4++) {
            int krow = t4 * 16 + lr;
            int sw = (krow & 7);
            short8v kfa = *(const short8v*)&Kf[krow * 64 + ((lg ^ sw) * 8)];
            short8v kfb = *(const short8v*)&Kf[krow * 64 + (((lg ^ 4) ^ sw) * 8)];
            sa[t4] = __builtin_amdgcn_mfma_f32_16x16x32_bf16(qf0a, kfa, sa[t4], 0, 0, 0);
            sa[t4] = __builtin_amdgcn_mfma_f32_16x16x32_bf16(qf1a, kfb, sa[t4], 0, 0, 0);
            if (dual) {
                sb[t4] = __builtin_amdgcn_mfma_f32_16x16x32_bf16(qf0b, kfa, sb[t4], 0, 0, 0);
                sb[t4] = __builtin_amdgcn_mfma_f32_16x16x32_bf16(qf1b, kfb, sb[t4], 0, 0, 0);
            }
        }
        __builtin_amdgcn_s_setprio(0);

        if (kv0 + 63 > q0a) {                // A causal boundary (last chunk only)
#pragma unroll
            for (int t4 = 0; t4 < 4; t4++)
#pragma unroll
                for (int r = 0; r < 4; r++)
                    if (kv0 + t4 * 16 + lr > q0a + lg * 4 + r) sa[t4][r] = -3e38f;
        }
        if (dual && kv0 + 63 > q0b) {        // B causal boundary (ci == p)
#pragma unroll
            for (int t4 = 0; t4 < 4; t4++)
#pragma unroll
                for (int r = 0; r < 4; r++)
                    if (kv0 + t4 * 16 + lr > q0b + lg * 4 + r) sb[t4][r] = -3e38f;
        }

        softmax_store(sa, mra, lsa, oa, 0);
        if (dual) softmax_store(sb, mrb, lsb, ob, 1);

        int prx = lr & 7;
        short8v pa0 = *(const short8v*)&p_lds[w][0][lr][8 * (lg ^ prx)];
        short8v pa1 = *(const short8v*)&p_lds[w][0][lr][8 * ((4 + lg) ^ prx)];
        short8v pb0, pb1;
        if (dual) {
            pb0 = *(const short8v*)&p_lds[w][1][lr][8 * (lg ^ prx)];
            pb1 = *(const short8v*)&p_lds[w][1][lr][8 * ((4 + lg) ^ prx)];
        }

        const short* Vf = (const short*)V_lds[cur];
        __builtin_amdgcn_s_setprio(1);
#pragma unroll
        for (int dt = 0; dt < 4; dt++) {
            int vrow = dt * 16 + lr;
            int sw = (vrow & 7);
            short8v vfa = *(const short8v*)&Vf[vrow * 64 + ((lg ^ sw) * 8)];
            short8v vfb = *(const short8v*)&Vf[vrow * 64 + (((lg ^ 4) ^ sw) * 8)];
            oa[dt] = __builtin_amdgcn_mfma_f32_16x16x32_bf16(pa0, vfa, oa[dt], 0, 0, 0);
            oa[dt] = __builtin_amdgcn_mfma_f32_16x16x32_bf16(pa1, vfb, oa[dt], 0, 0, 0);
            if (dual) {
                ob[dt] = __builtin_amdgcn_mfma_f32_16x16x32_bf16(pb0, vfa, ob[dt], 0, 0, 0);
                ob[dt] = __builtin_amdgcn_mfma_f32_16x16x32_bf16(pb1, vfb, ob[dt], 0, 0, 0);
            }
        }
        __builtin_amdgcn_s_setprio(0);

        __syncthreads();   // buffer flip: all reads of cur done + staging drained
        cur ^= 1;
    }

    // ---- finalize both sub-tiles ----
    float inva[4], invb[4];
#pragma unroll
    for (int r = 0; r < 4; r++) {
        float va = lsa[r], vb = lsb[r];
        va += __shfl_xor(va, 1); va += __shfl_xor(va, 2);
        va += __shfl_xor(va, 4); va += __shfl_xor(va, 8);
        vb += __shfl_xor(vb, 1); vb += __shfl_xor(vb, 2);
        vb += __shfl_xor(vb, 4); vb += __shfl_xor(vb, 8);
        inva[r] = 1.0f / va;
        invb[r] = 1.0f / vb;
    }
#pragma unroll
    for (int dt = 0; dt < 4; dt++)
#pragma unroll
        for (int r = 0; r < 4; r++) {
            int qa = q0a + lg * 4 + r;
            int qb = q0b + lg * 4 + r;
            Ob[((size_t)(b * 2048 + qa)) * 1024 + h * 64 + dt * 16 + lr] = f2bf(oa[dt][r] * inva[r]);
            Ob[((size_t)(b * 2048 + qb)) * 1024 + h * 64 + dt * 16 + lr] = f2bf(ob[dt][r] * invb[r]);
        }
}

extern "C" void kernel_launch(void* const* d_in, const int* in_sizes, int n_in,
                              void* d_out, int out_size, void* d_ws, size_t ws_size,
                              hipStream_t stream) {
    const float* x  = (const float*)d_in[0];
    const float* Wq = (const float*)d_in[1];
    const float* Wk = (const float*)d_in[2];
    const float* Wv = (const float*)d_in[3];
    const float* Wo = (const float*)d_in[4];
    float* out = (float*)d_out;

    char* ws = (char*)d_ws;
    short* xb  = (short*)(ws);                 // [4096][1024] bf16       8 MB
    short* Wtb = (short*)(ws + 8388608);       // 4 x [1024 n][1024 k]    8 MB
    short* Qb  = (short*)(ws + 16777216);      // [B,H,S,Dh] (pre-scaled) 8 MB
    short* Kb  = (short*)(ws + 25165824);      // [B,H,S,Dh]              8 MB
    short* Vtb = (short*)(ws + 33554432);      // [B,H,Dh,S]              8 MB
    short* Ob  = (short*)(ws + 41943040);      // [B,S,D] bf16            8 MB

    k_cvt_x<<<4096, 256, 0, stream>>>(x, xb);
    k_transpose<<<dim3(32, 32, 4), dim3(32, 8), 0, stream>>>(Wq, Wk, Wv, Wo, Wtb);
    k_gemmQKV<<<dim3(32, 8, 3), 512, 0, stream>>>(xb, Wtb, Qb, Kb, Vtb);
    k_attn<<<512, 256, 0, stream>>>(Qb, Kb, Vtb, Ob);
    k_gemmO<<<dim3(32, 8), 512, 0, stream>>>(Ob, Wtb + 3 * 1048576, out);
}

// Round 15
// 112.303 us; speedup vs baseline: 1.1344x; 1.0274x over previous
//
#include <hip/hip_runtime.h>

typedef __attribute__((ext_vector_type(4))) short short4v;
typedef __attribute__((ext_vector_type(8))) short short8v;
typedef __attribute__((ext_vector_type(4))) float float4v;
typedef __attribute__((ext_vector_type(4))) int int4v;

#define GLD_LDS16(gsrc, ldst)                                                             \
    __builtin_amdgcn_global_load_lds(                                                     \
        (const __attribute__((address_space(1))) void*)(gsrc),                            \
        (__attribute__((address_space(3))) void*)(ldst), 16, 0, 0)

__device__ __forceinline__ short f2bf(float f) {
    unsigned u = __builtin_bit_cast(unsigned, f);
    u += 0x7fffu + ((u >> 16) & 1u);
    return (short)(u >> 16);
}

__device__ __forceinline__ unsigned pk2(float a, float b) {
    return (unsigned)(unsigned short)f2bf(a) | ((unsigned)(unsigned short)f2bf(b) << 16);
}

// ---------------- x: fp32 -> bf16 (vectorized) ----------------
__global__ void k_cvt_x(const float* __restrict__ x, short* __restrict__ xb) {
    int i = blockIdx.x * blockDim.x + threadIdx.x;
    float4v v = ((const float4v*)x)[i];
    short4v o;
    o[0] = f2bf(v[0]); o[1] = f2bf(v[1]); o[2] = f2bf(v[2]); o[3] = f2bf(v[3]);
    ((short4v*)xb)[i] = o;
}

// ---------------- W[k][n] fp32 -> Wt[n][k] bf16 (LDS tile transpose) ----------------
__global__ void k_transpose(const float* __restrict__ W0, const float* __restrict__ W1,
                            const float* __restrict__ W2, const float* __restrict__ W3,
                            short* __restrict__ Wt) {
    const float* W = blockIdx.z == 0 ? W0 : blockIdx.z == 1 ? W1 : blockIdx.z == 2 ? W2 : W3;
    short* dst = Wt + (size_t)blockIdx.z * 1024 * 1024;
    __shared__ float tile[32][33];
    int x0 = blockIdx.x * 32, y0 = blockIdx.y * 32;
    int tx = threadIdx.x, ty = threadIdx.y;
#pragma unroll
    for (int j = 0; j < 4; j++) {
        int r = ty + j * 8;
        tile[r][tx] = W[(size_t)(y0 + r) * 1024 + x0 + tx];
    }
    __syncthreads();
#pragma unroll
    for (int j = 0; j < 4; j++) {
        int r = ty + j * 8;
        dst[(size_t)(x0 + r) * 1024 + y0 + tx] = f2bf(tile[tx][r]);
    }
}

// ---------------- merged QKV GEMM: 128x128 tile, BK=64, 8 waves, 2-phase dbuf --------
__launch_bounds__(512, 4)
__global__ void k_gemmQKV(const short* __restrict__ A, const short* __restrict__ Wtb,
                          short* __restrict__ Qb, short* __restrict__ Kb,
                          short* __restrict__ Vtb) {
    __shared__ short As[2][128][64];
    __shared__ short Bs[2][128][64];
    int t = threadIdx.x;
    int l = t & 63, w = t >> 6;
    int wm = w >> 2, wn = w & 3;
    int lr = l & 15, lg = l >> 4;
    int m0 = blockIdx.x * 128, n0 = blockIdx.y * 128;
    int which = blockIdx.z;
    const short* Bp = Wtb + ((size_t)which << 20);

    int srow = l >> 3;
    int sg = (l & 7) ^ srow;
    const short* Ab0 = A + (size_t)(m0 + w * 8 + srow) * 1024 + sg * 8;
    const short* Ab1 = Ab0 + 64 * 1024;
    const short* Bb0 = Bp + (size_t)(n0 + w * 8 + srow) * 1024 + sg * 8;
    const short* Bb1 = Bb0 + 64 * 1024;

    float4v acc[4][2] = {};

#define STAGE(bb, k0)                                   \
    do {                                                \
        GLD_LDS16(Ab0 + (k0), &As[bb][w * 8][0]);       \
        GLD_LDS16(Ab1 + (k0), &As[bb][64 + w * 8][0]);  \
        GLD_LDS16(Bb0 + (k0), &Bs[bb][w * 8][0]);       \
        GLD_LDS16(Bb1 + (k0), &Bs[bb][64 + w * 8][0]);  \
    } while (0)

    STAGE(0, 0);
    __syncthreads();
    int cur = 0;

    if (which == 2) {                        // block-uniform branch: V (swapped)
        for (int kt = 0; kt < 16; kt++) {
            if (kt + 1 < 16) STAGE(cur ^ 1, (kt + 1) * 64);
#pragma unroll
            for (int ks = 0; ks < 2; ks++) {
                short8v af[4], bfv[2];
                int hh = ks * 4 + lg;
                int sw = ((hh ^ (lr & 7)) * 8);
#pragma unroll
                for (int fm = 0; fm < 4; fm++)
                    af[fm] = *(const short8v*)&As[cur][wm * 64 + fm * 16 + lr][sw];
#pragma unroll
                for (int fn = 0; fn < 2; fn++)
                    bfv[fn] = *(const short8v*)&Bs[cur][wn * 32 + fn * 16 + lr][sw];
                __builtin_amdgcn_s_setprio(1);
#pragma unroll
                for (int fm = 0; fm < 4; fm++)
#pragma unroll
                    for (int fn = 0; fn < 2; fn++)
                        acc[fm][fn] = __builtin_amdgcn_mfma_f32_16x16x32_bf16(bfv[fn], af[fm], acc[fm][fn], 0, 0, 0);
                __builtin_amdgcn_s_setprio(0);
            }
            __syncthreads();
            cur ^= 1;
        }
    } else {
        for (int kt = 0; kt < 16; kt++) {
            if (kt + 1 < 16) STAGE(cur ^ 1, (kt + 1) * 64);
#pragma unroll
            for (int ks = 0; ks < 2; ks++) {
                short8v af[4], bfv[2];
                int hh = ks * 4 + lg;
                int sw = ((hh ^ (lr & 7)) * 8);
#pragma unroll
                for (int fm = 0; fm < 4; fm++)
                    af[fm] = *(const short8v*)&As[cur][wm * 64 + fm * 16 + lr][sw];
#pragma unroll
                for (int fn = 0; fn < 2; fn++)
                    bfv[fn] = *(const short8v*)&Bs[cur][wn * 32 + fn * 16 + lr][sw];
                __builtin_amdgcn_s_setprio(1);
#pragma unroll
                for (int fm = 0; fm < 4; fm++)
#pragma unroll
                    for (int fn = 0; fn < 2; fn++)
                        acc[fm][fn] = __builtin_amdgcn_mfma_f32_16x16x32_bf16(af[fm], bfv[fn], acc[fm][fn], 0, 0, 0);
                __builtin_amdgcn_s_setprio(0);
            }
            __syncthreads();
            cur ^= 1;
        }
    }
#undef STAGE

    if (which < 2) {
        short* out = (which == 0) ? Qb : Kb;
        float scale = (which == 0) ? 0.125f * 1.44269504088896f : 1.0f;
#pragma unroll
        for (int fm = 0; fm < 4; fm++)
#pragma unroll
            for (int fn = 0; fn < 2; fn++)
#pragma unroll
                for (int r = 0; r < 4; r++) {
                    int m = m0 + wm * 64 + fm * 16 + lg * 4 + r;
                    int n = n0 + wn * 32 + fn * 16 + lr;
                    float v = acc[fm][fn][r] * scale;
                    int b = m >> 11, s = m & 2047, h = n >> 6, dh = n & 63;
                    out[(((size_t)(b * 16 + h)) * 2048 + s) * 64 + dh] = f2bf(v);
                }
    } else {
#pragma unroll
        for (int fm = 0; fm < 4; fm++)
#pragma unroll
            for (int fn = 0; fn < 2; fn++)
#pragma unroll
                for (int r = 0; r < 4; r++) {
                    int n = n0 + wn * 32 + fn * 16 + lg * 4 + r;
                    int m = m0 + wm * 64 + fm * 16 + lr;
                    int b = m >> 11, s = m & 2047, h = n >> 6, dh = n & 63;
                    Vtb[(((size_t)(b * 16 + h)) * 64 + dh) * 2048 + s] = f2bf(acc[fm][fn][r]);
                }
    }
}

// ---------------- O-projection GEMM (fp32 out) ----------------
__launch_bounds__(512, 4)
__global__ void k_gemmO(const short* __restrict__ A, const short* __restrict__ Bt,
                        float* __restrict__ outF) {
    __shared__ short As[2][128][64];
    __shared__ short Bs[2][128][64];
    int t = threadIdx.x;
    int l = t & 63, w = t >> 6;
    int wm = w >> 2, wn = w & 3;
    int lr = l & 15, lg = l >> 4;
    int m0 = blockIdx.x * 128, n0 = blockIdx.y * 128;

    int srow = l >> 3;
    int sg = (l & 7) ^ srow;
    const short* Ab0 = A + (size_t)(m0 + w * 8 + srow) * 1024 + sg * 8;
    const short* Ab1 = Ab0 + 64 * 1024;
    const short* Bb0 = Bt + (size_t)(n0 + w * 8 + srow) * 1024 + sg * 8;
    const short* Bb1 = Bb0 + 64 * 1024;

    float4v acc[4][2] = {};

#define STAGE(bb, k0)                                   \
    do {                                                \
        GLD_LDS16(Ab0 + (k0), &As[bb][w * 8][0]);       \
        GLD_LDS16(Ab1 + (k0), &As[bb][64 + w * 8][0]);  \
        GLD_LDS16(Bb0 + (k0), &Bs[bb][w * 8][0]);       \
        GLD_LDS16(Bb1 + (k0), &Bs[bb][64 + w * 8][0]);  \
    } while (0)

    STAGE(0, 0);
    __syncthreads();
    int cur = 0;

    for (int kt = 0; kt < 16; kt++) {
        if (kt + 1 < 16) STAGE(cur ^ 1, (kt + 1) * 64);
#pragma unroll
        for (int ks = 0; ks < 2; ks++) {
            short8v af[4], bfv[2];
            int hh = ks * 4 + lg;
            int sw = ((hh ^ (lr & 7)) * 8);
#pragma unroll
            for (int fm = 0; fm < 4; fm++)
                af[fm] = *(const short8v*)&As[cur][wm * 64 + fm * 16 + lr][sw];
#pragma unroll
            for (int fn = 0; fn < 2; fn++)
                bfv[fn] = *(const short8v*)&Bs[cur][wn * 32 + fn * 16 + lr][sw];
            __builtin_amdgcn_s_setprio(1);
#pragma unroll
            for (int fm = 0; fm < 4; fm++)
#pragma unroll
                for (int fn = 0; fn < 2; fn++)
                    acc[fm][fn] = __builtin_amdgcn_mfma_f32_16x16x32_bf16(af[fm], bfv[fn], acc[fm][fn], 0, 0, 0);
            __builtin_amdgcn_s_setprio(0);
        }
        __syncthreads();
        cur ^= 1;
    }
#undef STAGE

#pragma unroll
    for (int fm = 0; fm < 4; fm++)
#pragma unroll
        for (int fn = 0; fn < 2; fn++)
#pragma unroll
            for (int r = 0; r < 4; r++) {
                int m = m0 + wm * 64 + fm * 16 + lg * 4 + r;
                int n = n0 + wn * 32 + fn * 16 + lr;
                outF[(size_t)m * 1024 + n] = acc[fm][fn][r];
            }
}

// ---------------- causal flash attention v14: swapped QK^T + packed P writes ----
// v13 skeleton (stripe-paired grid, 4-wave blocks, swizzled K/V in dbuf LDS).
// QK^T computed as mfma(K,Q): lane (lr,lg) holds S[kv=16t4+4lg+r][q=lr] ->
// softmax is lane-local scalar; P written as 4 ds_write_b64/subtile (was 16 b16).
// P read layout unchanged (conflict-free b128 A-fragments).
__launch_bounds__(256, 2)
__global__ void k_attn(const short* __restrict__ Qb, const short* __restrict__ Kb,
                       const short* __restrict__ Vtb, short* __restrict__ Ob) {
    __shared__ short K_lds[2][64][64];
    __shared__ short V_lds[2][64][64];
    __shared__ short p_lds[4][2][16][64];
    int t = threadIdx.x;
    int l = t & 63, w = t >> 6;
    int lr = l & 15, lg = l >> 4;

    int L = blockIdx.x;                      // 0..511
    int bh = L & 31;                         // L%8 = bh%8 -> XCD affinity
    int g = L >> 5;                          // 0..15
    int p = (g < 8) ? g : 23 - g;            // heavy first; CU pair sums constant
    int nch = 32 - p;                        // staged chunks (covers hi tile)

    const short* Qp = Qb + (size_t)bh * 2048 * 64;
    const short* Kp = Kb + (size_t)bh * 2048 * 64;
    const short* Vp = Vtb + (size_t)bh * 64 * 2048;

    auto stage = [&](int bb, int kv0) {
#pragma unroll
        for (int i = 0; i < 2; i++) {
            int s = t + i * 256;
            int row = s >> 3, cg = s & 7;
            int cs = (cg ^ (row & 7)) * 8;
            GLD_LDS16(&Kp[(size_t)(kv0 + row) * 64 + cs], (short*)K_lds[bb] + (size_t)s * 8);
            GLD_LDS16(&Vp[(size_t)row * 2048 + kv0 + cs], (short*)V_lds[bb] + (size_t)s * 8);
        }
    };

    stage(0, 0);

    int q0a = (31 - p) * 64 + w * 16;        // sub-tile A rows (hi tile)
    int q0b = p * 64 + w * 16;               // sub-tile B rows (lo tile)
    short8v qf0a = *(const short8v*)&Qp[(size_t)(q0a + lr) * 64 + lg * 8];
    short8v qf1a = *(const short8v*)&Qp[(size_t)(q0a + lr) * 64 + 32 + lg * 8];
    short8v qf0b = *(const short8v*)&Qp[(size_t)(q0b + lr) * 64 + lg * 8];
    short8v qf1b = *(const short8v*)&Qp[(size_t)(q0b + lr) * 64 + 32 + lg * 8];

    float4v oa[4] = {}, ob[4] = {};
    float mra = -3e38f, mrb = -3e38f;        // running max for q = lr (lane-local)
    float lsa = 0.f, lsb = 0.f;              // partial row-sum (this lane's kv share)
    int cur = 0;
    int b = bh >> 4, h = bh & 15;

    // swapped-layout softmax + packed P store: lane holds S[kv=16t4+4lg+r][q=lr]
    auto softmax_store = [&](float4v (&s)[4], float& mr, float& ls,
                             float4v (&o)[4], int X) {
        float mx = -3e38f;
#pragma unroll
        for (int t4 = 0; t4 < 4; t4++)
#pragma unroll
            for (int r = 0; r < 4; r++) mx = fmaxf(mx, s[t4][r]);

        if (!__all(mx - mr <= 8.f)) {        // rare: first chunk / big max jump
            float m_ = fmaxf(mx, __shfl_xor(mx, 16));
            m_ = fmaxf(m_, __shfl_xor(m_, 32));
            float mnew = fmaxf(mr, m_);
            float sc = __builtin_amdgcn_exp2f(mr - mnew);
            mr = mnew;
            ls *= sc;
#pragma unroll
            for (int r = 0; r < 4; r++) {
                float scq = __shfl(sc, lg * 4 + r);   // scale for O's q-row 4lg+r
                o[0][r] *= scq; o[1][r] *= scq; o[2][r] *= scq; o[3][r] *= scq;
            }
        }
        int rx = lr & 7;
        int half = (lg & 1) * 4;
#pragma unroll
        for (int t4 = 0; t4 < 4; t4++) {
            float e0 = __builtin_amdgcn_exp2f(s[t4][0] - mr);
            float e1 = __builtin_amdgcn_exp2f(s[t4][1] - mr);
            float e2 = __builtin_amdgcn_exp2f(s[t4][2] - mr);
            float e3 = __builtin_amdgcn_exp2f(s[t4][3] - mr);
            ls += (e0 + e1) + (e2 + e3);
            unsigned lo = pk2(e0, e1), hi = pk2(e2, e3);
            int grp = (2 * t4 + (lg >> 1)) ^ rx;
            *(unsigned long long*)&p_lds[w][X][lr][grp * 8 + half] =
                (unsigned long long)lo | ((unsigned long long)hi << 32);
        }
    };

    __syncthreads();   // prologue stage drained

    for (int ci = 0; ci < nch; ci++) {
        int kv0 = ci * 64;
        bool dual = (ci <= p);               // block-uniform: B sub-tile active

        if (ci + 1 < nch) stage(cur ^ 1, (ci + 1) * 64);

        const short* Kf = (const short*)K_lds[cur];
        float4v sa[4] = {}, sb[4] = {};
        __builtin_amdgcn_s_setprio(1);
#pragma unroll
        for (int t4 = 0; t4 < 4; t4++) {
            int krow = t4 * 16 + lr;
            int sw = (krow & 7);
            short8v kfa = *(const short8v*)&Kf[krow * 64 + ((lg ^ sw) * 8)];
            short8v kfb = *(const short8v*)&Kf[krow * 64 + (((lg ^ 4) ^ sw) * 8)];
            sa[t4] = __builtin_amdgcn_mfma_f32_16x16x32_bf16(kfa, qf0a, sa[t4], 0, 0, 0);
            sa[t4] = __builtin_amdgcn_mfma_f32_16x16x32_bf16(kfb, qf1a, sa[t4], 0, 0, 0);
            if (dual) {
                sb[t4] = __builtin_amdgcn_mfma_f32_16x16x32_bf16(kfa, qf0b, sb[t4], 0, 0, 0);
                sb[t4] = __builtin_amdgcn_mfma_f32_16x16x32_bf16(kfb, qf1b, sb[t4], 0, 0, 0);
            }
        }
        __builtin_amdgcn_s_setprio(0);

        // swapped layout: lane holds S[kv=kv0+16t4+4lg+r][q=q0+lr]
        if (kv0 + 63 > q0a) {
#pragma unroll
            for (int t4 = 0; t4 < 4; t4++)
#pragma unroll
                for (int r = 0; r < 4; r++)
                    if (kv0 + t4 * 16 + 4 * lg + r > q0a + lr) sa[t4][r] = -3e38f;
        }
        if (dual && kv0 + 63 > q0b) {
#pragma unroll
            for (int t4 = 0; t4 < 4; t4++)
#pragma unroll
                for (int r = 0; r < 4; r++)
                    if (kv0 + t4 * 16 + 4 * lg + r > q0b + lr) sb[t4][r] = -3e38f;
        }

        softmax_store(sa, mra, lsa, oa, 0);
        if (dual) softmax_store(sb, mrb, lsb, ob, 1);

        int prx = lr & 7;
        short8v pa0 = *(const short8v*)&p_lds[w][0][lr][8 * (lg ^ prx)];
        short8v pa1 = *(const short8v*)&p_lds[w][0][lr][8 * ((4 + lg) ^ prx)];
        short8v pb0, pb1;
        if (dual) {
            pb0 = *(const short8v*)&p_lds[w][1][lr][8 * (lg ^ prx)];
            pb1 = *(const short8v*)&p_lds[w][1][lr][8 * ((4 + lg) ^ prx)];
        }

        const short* Vf = (const short*)V_lds[cur];
        __builtin_amdgcn_s_setprio(1);
#pragma unroll
        for (int dt = 0; dt < 4; dt++) {
            int vrow = dt * 16 + lr;
            int sw = (vrow & 7);
            short8v vfa = *(const short8v*)&Vf[vrow * 64 + ((lg ^ sw) * 8)];
            short8v vfb = *(const short8v*)&Vf[vrow * 64 + (((lg ^ 4) ^ sw) * 8)];
            oa[dt] = __builtin_amdgcn_mfma_f32_16x16x32_bf16(pa0, vfa, oa[dt], 0, 0, 0);
            oa[dt] = __builtin_amdgcn_mfma_f32_16x16x32_bf16(pa1, vfb, oa[dt], 0, 0, 0);
            if (dual) {
                ob[dt] = __builtin_amdgcn_mfma_f32_16x16x32_bf16(pb0, vfa, ob[dt], 0, 0, 0);
                ob[dt] = __builtin_amdgcn_mfma_f32_16x16x32_bf16(pb1, vfb, ob[dt], 0, 0, 0);
            }
        }
        __builtin_amdgcn_s_setprio(0);

        __syncthreads();   // buffer flip: all reads of cur done + staging drained
        cur ^= 1;
    }

    // ---- finalize both sub-tiles (row-sum across lg partials, shfl inverse) ----
    float la = lsa, lb = lsb;
    la += __shfl_xor(la, 16); la += __shfl_xor(la, 32);
    lb += __shfl_xor(lb, 16); lb += __shfl_xor(lb, 32);
    float inva_ = 1.0f / la, invb_ = 1.0f / lb;   // valid for q-row lr
    float inva[4], invb[4];
#pragma unroll
    for (int r = 0; r < 4; r++) {
        inva[r] = __shfl(inva_, lg * 4 + r);
        invb[r] = __shfl(invb_, lg * 4 + r);
    }
#pragma unroll
    for (int dt = 0; dt < 4; dt++)
#pragma unroll
        for (int r = 0; r < 4; r++) {
            int qa = q0a + lg * 4 + r;
            int qb = q0b + lg * 4 + r;
            Ob[((size_t)(b * 2048 + qa)) * 1024 + h * 64 + dt * 16 + lr] = f2bf(oa[dt][r] * inva[r]);
            Ob[((size_t)(b * 2048 + qb)) * 1024 + h * 64 + dt * 16 + lr] = f2bf(ob[dt][r] * invb[r]);
        }
}

extern "C" void kernel_launch(void* const* d_in, const int* in_sizes, int n_in,
                              void* d_out, int out_size, void* d_ws, size_t ws_size,
                              hipStream_t stream) {
    const float* x  = (const float*)d_in[0];
    const float* Wq = (const float*)d_in[1];
    const float* Wk = (const float*)d_in[2];
    const float* Wv = (const float*)d_in[3];
    const float* Wo = (const float*)d_in[4];
    float* out = (float*)d_out;

    char* ws = (char*)d_ws;
    short* xb  = (short*)(ws);                 // [4096][1024] bf16       8 MB
    short* Wtb = (short*)(ws + 8388608);       // 4 x [1024 n][1024 k]    8 MB
    short* Qb  = (short*)(ws + 16777216);      // [B,H,S,Dh] (pre-scaled) 8 MB
    short* Kb  = (short*)(ws + 25165824);      // [B,H,S,Dh]              8 MB
    short* Vtb = (short*)(ws + 33554432);      // [B,H,Dh,S]              8 MB
    short* Ob  = (short*)(ws + 41943040);      // [B,S,D] bf16            8 MB

    k_cvt_x<<<4096, 256, 0, stream>>>(x, xb);
    k_transpose<<<dim3(32, 32, 4), dim3(32, 8), 0, stream>>>(Wq, Wk, Wv, Wo, Wtb);
    k_gemmQKV<<<dim3(32, 8, 3), 512, 0, stream>>>(xb, Wtb, Qb, Kb, Vtb);
    k_attn<<<512, 256, 0, stream>>>(Qb, Kb, Vtb, Ob);
    k_gemmO<<<dim3(32, 8), 512, 0, stream>>>(Ob, Wtb + 3 * 1048576, out);
}

// Round 16
// 106.812 us; speedup vs baseline: 1.1927x; 1.0514x over previous
//
#include <hip/hip_runtime.h>

typedef __attribute__((ext_vector_type(4))) short short4v;
typedef __attribute__((ext_vector_type(8))) short short8v;
typedef __attribute__((ext_vector_type(4))) float float4v;
typedef __attribute__((ext_vector_type(4))) int int4v;

#define GLD_LDS16(gsrc, ldst)                                                             \
    __builtin_amdgcn_global_load_lds(                                                     \
        (const __attribute__((address_space(1))) void*)(gsrc),                            \
        (__attribute__((address_space(3))) void*)(ldst), 16, 0, 0)

__device__ __forceinline__ short f2bf(float f) {
    unsigned u = __builtin_bit_cast(unsigned, f);
    u += 0x7fffu + ((u >> 16) & 1u);
    return (short)(u >> 16);
}

// ---------------- fused prep: x cvt (blocks 0..4095) + W transpose (4096..8191) ----
__global__ void k_prep(const float* __restrict__ x, short* __restrict__ xb,
                       const float* __restrict__ W0, const float* __restrict__ W1,
                       const float* __restrict__ W2, const float* __restrict__ W3,
                       short* __restrict__ Wt) {
    __shared__ float tile[32][33];
    int bid = blockIdx.x;
    if (bid < 4096) {
        int i = bid * 256 + threadIdx.x;
        float4v v = ((const float4v*)x)[i];
        short4v o;
        o[0] = f2bf(v[0]); o[1] = f2bf(v[1]); o[2] = f2bf(v[2]); o[3] = f2bf(v[3]);
        ((short4v*)xb)[i] = o;
        return;
    }
    int L = bid - 4096;                  // 0..4095
    int z = L >> 10;                     // weight 0..3
    int xy = L & 1023;
    int bx = xy & 31, by = xy >> 5;
    const float* W = z == 0 ? W0 : z == 1 ? W1 : z == 2 ? W2 : W3;
    short* dst = Wt + (size_t)z * 1024 * 1024;
    int x0 = bx * 32, y0 = by * 32;
    int tx = threadIdx.x & 31, ty = threadIdx.x >> 5;   // 32 x 8
#pragma unroll
    for (int j = 0; j < 4; j++) {
        int r = ty + j * 8;
        tile[r][tx] = W[(size_t)(y0 + r) * 1024 + x0 + tx];
    }
    __syncthreads();
#pragma unroll
    for (int j = 0; j < 4; j++) {
        int r = ty + j * 8;
        dst[(size_t)(x0 + r) * 1024 + y0 + tx] = f2bf(tile[tx][r]);
    }
}

// ---------------- merged QKV GEMM: 128x128 tile, BK=64, 8 waves, 2-phase dbuf --------
__launch_bounds__(512, 4)
__global__ void k_gemmQKV(const short* __restrict__ A, const short* __restrict__ Wtb,
                          short* __restrict__ Qb, short* __restrict__ Kb,
                          short* __restrict__ Vtb) {
    __shared__ short As[2][128][64];
    __shared__ short Bs[2][128][64];
    int t = threadIdx.x;
    int l = t & 63, w = t >> 6;
    int wm = w >> 2, wn = w & 3;
    int lr = l & 15, lg = l >> 4;
    int m0 = blockIdx.x * 128, n0 = blockIdx.y * 128;
    int which = blockIdx.z;
    const short* Bp = Wtb + ((size_t)which << 20);

    int srow = l >> 3;
    int sg = (l & 7) ^ srow;
    const short* Ab0 = A + (size_t)(m0 + w * 8 + srow) * 1024 + sg * 8;
    const short* Ab1 = Ab0 + 64 * 1024;
    const short* Bb0 = Bp + (size_t)(n0 + w * 8 + srow) * 1024 + sg * 8;
    const short* Bb1 = Bb0 + 64 * 1024;

    float4v acc[4][2] = {};

#define STAGE(bb, k0)                                   \
    do {                                                \
        GLD_LDS16(Ab0 + (k0), &As[bb][w * 8][0]);       \
        GLD_LDS16(Ab1 + (k0), &As[bb][64 + w * 8][0]);  \
        GLD_LDS16(Bb0 + (k0), &Bs[bb][w * 8][0]);       \
        GLD_LDS16(Bb1 + (k0), &Bs[bb][64 + w * 8][0]);  \
    } while (0)

    STAGE(0, 0);
    __syncthreads();
    int cur = 0;

    if (which == 2) {                        // block-uniform branch: V (swapped)
        for (int kt = 0; kt < 16; kt++) {
            if (kt + 1 < 16) STAGE(cur ^ 1, (kt + 1) * 64);
#pragma unroll
            for (int ks = 0; ks < 2; ks++) {
                short8v af[4], bfv[2];
                int hh = ks * 4 + lg;
                int sw = ((hh ^ (lr & 7)) * 8);
#pragma unroll
                for (int fm = 0; fm < 4; fm++)
                    af[fm] = *(const short8v*)&As[cur][wm * 64 + fm * 16 + lr][sw];
#pragma unroll
                for (int fn = 0; fn < 2; fn++)
                    bfv[fn] = *(const short8v*)&Bs[cur][wn * 32 + fn * 16 + lr][sw];
                __builtin_amdgcn_s_setprio(1);
#pragma unroll
                for (int fm = 0; fm < 4; fm++)
#pragma unroll
                    for (int fn = 0; fn < 2; fn++)
                        acc[fm][fn] = __builtin_amdgcn_mfma_f32_16x16x32_bf16(bfv[fn], af[fm], acc[fm][fn], 0, 0, 0);
                __builtin_amdgcn_s_setprio(0);
            }
            __syncthreads();
            cur ^= 1;
        }
    } else {
        for (int kt = 0; kt < 16; kt++) {
            if (kt + 1 < 16) STAGE(cur ^ 1, (kt + 1) * 64);
#pragma unroll
            for (int ks = 0; ks < 2; ks++) {
                short8v af[4], bfv[2];
                int hh = ks * 4 + lg;
                int sw = ((hh ^ (lr & 7)) * 8);
#pragma unroll
                for (int fm = 0; fm < 4; fm++)
                    af[fm] = *(const short8v*)&As[cur][wm * 64 + fm * 16 + lr][sw];
#pragma unroll
                for (int fn = 0; fn < 2; fn++)
                    bfv[fn] = *(const short8v*)&Bs[cur][wn * 32 + fn * 16 + lr][sw];
                __builtin_amdgcn_s_setprio(1);
#pragma unroll
                for (int fm = 0; fm < 4; fm++)
#pragma unroll
                    for (int fn = 0; fn < 2; fn++)
                        acc[fm][fn] = __builtin_amdgcn_mfma_f32_16x16x32_bf16(af[fm], bfv[fn], acc[fm][fn], 0, 0, 0);
                __builtin_amdgcn_s_setprio(0);
            }
            __syncthreads();
            cur ^= 1;
        }
    }
#undef STAGE

    if (which < 2) {
        short* out = (which == 0) ? Qb : Kb;
        float scale = (which == 0) ? 0.125f * 1.44269504088896f : 1.0f;
#pragma unroll
        for (int fm = 0; fm < 4; fm++)
#pragma unroll
            for (int fn = 0; fn < 2; fn++)
#pragma unroll
                for (int r = 0; r < 4; r++) {
                    int m = m0 + wm * 64 + fm * 16 + lg * 4 + r;
                    int n = n0 + wn * 32 + fn * 16 + lr;
                    float v = acc[fm][fn][r] * scale;
                    int b = m >> 11, s = m & 2047, h = n >> 6, dh = n & 63;
                    out[(((size_t)(b * 16 + h)) * 2048 + s) * 64 + dh] = f2bf(v);
                }
    } else {
#pragma unroll
        for (int fm = 0; fm < 4; fm++)
#pragma unroll
            for (int fn = 0; fn < 2; fn++)
#pragma unroll
                for (int r = 0; r < 4; r++) {
                    int n = n0 + wn * 32 + fn * 16 + lg * 4 + r;
                    int m = m0 + wm * 64 + fm * 16 + lr;
                    int b = m >> 11, s = m & 2047, h = n >> 6, dh = n & 63;
                    Vtb[(((size_t)(b * 16 + h)) * 64 + dh) * 2048 + s] = f2bf(acc[fm][fn][r]);
                }
    }
}

// ---------------- O-projection GEMM (fp32 out) ----------------
__launch_bounds__(512, 4)
__global__ void k_gemmO(const short* __restrict__ A, const short* __restrict__ Bt,
                        float* __restrict__ outF) {
    __shared__ short As[2][128][64];
    __shared__ short Bs[2][128][64];
    int t = threadIdx.x;
    int l = t & 63, w = t >> 6;
    int wm = w >> 2, wn = w & 3;
    int lr = l & 15, lg = l >> 4;
    int m0 = blockIdx.x * 128, n0 = blockIdx.y * 128;

    int srow = l >> 3;
    int sg = (l & 7) ^ srow;
    const short* Ab0 = A + (size_t)(m0 + w * 8 + srow) * 1024 + sg * 8;
    const short* Ab1 = Ab0 + 64 * 1024;
    const short* Bb0 = Bt + (size_t)(n0 + w * 8 + srow) * 1024 + sg * 8;
    const short* Bb1 = Bb0 + 64 * 1024;

    float4v acc[4][2] = {};

#define STAGE(bb, k0)                                   \
    do {                                                \
        GLD_LDS16(Ab0 + (k0), &As[bb][w * 8][0]);       \
        GLD_LDS16(Ab1 + (k0), &As[bb][64 + w * 8][0]);  \
        GLD_LDS16(Bb0 + (k0), &Bs[bb][w * 8][0]);       \
        GLD_LDS16(Bb1 + (k0), &Bs[bb][64 + w * 8][0]);  \
    } while (0)

    STAGE(0, 0);
    __syncthreads();
    int cur = 0;

    for (int kt = 0; kt < 16; kt++) {
        if (kt + 1 < 16) STAGE(cur ^ 1, (kt + 1) * 64);
#pragma unroll
        for (int ks = 0; ks < 2; ks++) {
            short8v af[4], bfv[2];
            int hh = ks * 4 + lg;
            int sw = ((hh ^ (lr & 7)) * 8);
#pragma unroll
            for (int fm = 0; fm < 4; fm++)
                af[fm] = *(const short8v*)&As[cur][wm * 64 + fm * 16 + lr][sw];
#pragma unroll
            for (int fn = 0; fn < 2; fn++)
                bfv[fn] = *(const short8v*)&Bs[cur][wn * 32 + fn * 16 + lr][sw];
            __builtin_amdgcn_s_setprio(1);
#pragma unroll
            for (int fm = 0; fm < 4; fm++)
#pragma unroll
                for (int fn = 0; fn < 2; fn++)
                    acc[fm][fn] = __builtin_amdgcn_mfma_f32_16x16x32_bf16(af[fm], bfv[fn], acc[fm][fn], 0, 0, 0);
            __builtin_amdgcn_s_setprio(0);
        }
        __syncthreads();
        cur ^= 1;
    }
#undef STAGE

#pragma unroll
    for (int fm = 0; fm < 4; fm++)
#pragma unroll
        for (int fn = 0; fn < 2; fn++)
#pragma unroll
            for (int r = 0; r < 4; r++) {
                int m = m0 + wm * 64 + fm * 16 + lg * 4 + r;
                int n = n0 + wn * 32 + fn * 16 + lr;
                outF[(size_t)m * 1024 + n] = acc[fm][fn][r];
            }
}

// ---------------- causal flash attention v15: v14 + cvt_pk packed P writes ----
__launch_bounds__(256, 2)
__global__ void k_attn(const short* __restrict__ Qb, const short* __restrict__ Kb,
                       const short* __restrict__ Vtb, short* __restrict__ Ob) {
    __shared__ short K_lds[2][64][64];
    __shared__ short V_lds[2][64][64];
    __shared__ short p_lds[4][2][16][64];
    int t = threadIdx.x;
    int l = t & 63, w = t >> 6;
    int lr = l & 15, lg = l >> 4;

    int L = blockIdx.x;                      // 0..511
    int bh = L & 31;                         // L%8 = bh%8 -> XCD affinity
    int g = L >> 5;                          // 0..15
    int p = (g < 8) ? g : 23 - g;            // heavy first; CU pair sums constant
    int nch = 32 - p;                        // staged chunks (covers hi tile)

    const short* Qp = Qb + (size_t)bh * 2048 * 64;
    const short* Kp = Kb + (size_t)bh * 2048 * 64;
    const short* Vp = Vtb + (size_t)bh * 64 * 2048;

    auto stage = [&](int bb, int kv0) {
#pragma unroll
        for (int i = 0; i < 2; i++) {
            int s = t + i * 256;
            int row = s >> 3, cg = s & 7;
            int cs = (cg ^ (row & 7)) * 8;
            GLD_LDS16(&Kp[(size_t)(kv0 + row) * 64 + cs], (short*)K_lds[bb] + (size_t)s * 8);
            GLD_LDS16(&Vp[(size_t)row * 2048 + kv0 + cs], (short*)V_lds[bb] + (size_t)s * 8);
        }
    };

    stage(0, 0);

    int q0a = (31 - p) * 64 + w * 16;        // sub-tile A rows (hi tile)
    int q0b = p * 64 + w * 16;               // sub-tile B rows (lo tile)
    short8v qf0a = *(const short8v*)&Qp[(size_t)(q0a + lr) * 64 + lg * 8];
    short8v qf1a = *(const short8v*)&Qp[(size_t)(q0a + lr) * 64 + 32 + lg * 8];
    short8v qf0b = *(const short8v*)&Qp[(size_t)(q0b + lr) * 64 + lg * 8];
    short8v qf1b = *(const short8v*)&Qp[(size_t)(q0b + lr) * 64 + 32 + lg * 8];

    float4v oa[4] = {}, ob[4] = {};
    float mra = -3e38f, mrb = -3e38f;        // running max for q = lr (lane-local)
    float lsa = 0.f, lsb = 0.f;              // partial row-sum (this lane's kv share)
    int cur = 0;
    int b = bh >> 4, h = bh & 15;

    // swapped-layout softmax + packed P store (v_cvt_pk_bf16_f32, T12 recipe)
    auto softmax_store = [&](float4v (&s)[4], float& mr, float& ls,
                             float4v (&o)[4], int X) {
        float mx = -3e38f;
#pragma unroll
        for (int t4 = 0; t4 < 4; t4++)
#pragma unroll
            for (int r = 0; r < 4; r++) mx = fmaxf(mx, s[t4][r]);

        if (!__all(mx - mr <= 8.f)) {        // rare: first chunk / big max jump
            float m_ = fmaxf(mx, __shfl_xor(mx, 16));
            m_ = fmaxf(m_, __shfl_xor(m_, 32));
            float mnew = fmaxf(mr, m_);
            float sc = __builtin_amdgcn_exp2f(mr - mnew);
            mr = mnew;
            ls *= sc;
#pragma unroll
            for (int r = 0; r < 4; r++) {
                float scq = __shfl(sc, lg * 4 + r);   // scale for O's q-row 4lg+r
                o[0][r] *= scq; o[1][r] *= scq; o[2][r] *= scq; o[3][r] *= scq;
            }
        }
        int rx = lr & 7;
        int half = (lg & 1) * 4;
#pragma unroll
        for (int t4 = 0; t4 < 4; t4++) {
            float e0 = __builtin_amdgcn_exp2f(s[t4][0] - mr);
            float e1 = __builtin_amdgcn_exp2f(s[t4][1] - mr);
            float e2 = __builtin_amdgcn_exp2f(s[t4][2] - mr);
            float e3 = __builtin_amdgcn_exp2f(s[t4][3] - mr);
            ls += (e0 + e1) + (e2 + e3);
            unsigned lo, hi;
            asm("v_cvt_pk_bf16_f32 %0, %1, %2" : "=v"(lo) : "v"(e0), "v"(e1));
            asm("v_cvt_pk_bf16_f32 %0, %1, %2" : "=v"(hi) : "v"(e2), "v"(e3));
            int grp = (2 * t4 + (lg >> 1)) ^ rx;
            *(unsigned long long*)&p_lds[w][X][lr][grp * 8 + half] =
                (unsigned long long)lo | ((unsigned long long)hi << 32);
        }
    };

    __syncthreads();   // prologue stage drained

    for (int ci = 0; ci < nch; ci++) {
        int kv0 = ci * 64;
        bool dual = (ci <= p);               // block-uniform: B sub-tile active

        if (ci + 1 < nch) stage(cur ^ 1, (ci + 1) * 64);

        const short* Kf = (const short*)K_lds[cur];
        float4v sa[4] = {}, sb[4] = {};
        __builtin_amdgcn_s_setprio(1);
#pragma unroll
        for (int t4 = 0; t4 < 4; t4++) {
            int krow = t4 * 16 + lr;
            int sw = (krow & 7);
            short8v kfa = *(const short8v*)&Kf[krow * 64 + ((lg ^ sw) * 8)];
            short8v kfb = *(const short8v*)&Kf[krow * 64 + (((lg ^ 4) ^ sw) * 8)];
            sa[t4] = __builtin_amdgcn_mfma_f32_16x16x32_bf16(kfa, qf0a, sa[t4], 0, 0, 0);
            sa[t4] = __builtin_amdgcn_mfma_f32_16x16x32_bf16(kfb, qf1a, sa[t4], 0, 0, 0);
            if (dual) {
                sb[t4] = __builtin_amdgcn_mfma_f32_16x16x32_bf16(kfa, qf0b, sb[t4], 0, 0, 0);
                sb[t4] = __builtin_amdgcn_mfma_f32_16x16x32_bf16(kfb, qf1b, sb[t4], 0, 0, 0);
            }
        }
        __builtin_amdgcn_s_setprio(0);

        // swapped layout: lane holds S[kv=kv0+16t4+4lg+r][q=q0+lr]
        if (kv0 + 63 > q0a) {
#pragma unroll
            for (int t4 = 0; t4 < 4; t4++)
#pragma unroll
                for (int r = 0; r < 4; r++)
                    if (kv0 + t4 * 16 + 4 * lg + r > q0a + lr) sa[t4][r] = -3e38f;
        }
        if (dual && kv0 + 63 > q0b) {
#pragma unroll
            for (int t4 = 0; t4 < 4; t4++)
#pragma unroll
                for (int r = 0; r < 4; r++)
                    if (kv0 + t4 * 16 + 4 * lg + r > q0b + lr) sb[t4][r] = -3e38f;
        }

        softmax_store(sa, mra, lsa, oa, 0);
        if (dual) softmax_store(sb, mrb, lsb, ob, 1);

        int prx = lr & 7;
        short8v pa0 = *(const short8v*)&p_lds[w][0][lr][8 * (lg ^ prx)];
        short8v pa1 = *(const short8v*)&p_lds[w][0][lr][8 * ((4 + lg) ^ prx)];
        short8v pb0, pb1;
        if (dual) {
            pb0 = *(const short8v*)&p_lds[w][1][lr][8 * (lg ^ prx)];
            pb1 = *(const short8v*)&p_lds[w][1][lr][8 * ((4 + lg) ^ prx)];
        }

        const short* Vf = (const short*)V_lds[cur];
        __builtin_amdgcn_s_setprio(1);
#pragma unroll
        for (int dt = 0; dt < 4; dt++) {
            int vrow = dt * 16 + lr;
            int sw = (vrow & 7);
            short8v vfa = *(const short8v*)&Vf[vrow * 64 + ((lg ^ sw) * 8)];
            short8v vfb = *(const short8v*)&Vf[vrow * 64 + (((lg ^ 4) ^ sw) * 8)];
            oa[dt] = __builtin_amdgcn_mfma_f32_16x16x32_bf16(pa0, vfa, oa[dt], 0, 0, 0);
            oa[dt] = __builtin_amdgcn_mfma_f32_16x16x32_bf16(pa1, vfb, oa[dt], 0, 0, 0);
            if (dual) {
                ob[dt] = __builtin_amdgcn_mfma_f32_16x16x32_bf16(pb0, vfa, ob[dt], 0, 0, 0);
                ob[dt] = __builtin_amdgcn_mfma_f32_16x16x32_bf16(pb1, vfb, ob[dt], 0, 0, 0);
            }
        }
        __builtin_amdgcn_s_setprio(0);

        __syncthreads();   // buffer flip: all reads of cur done + staging drained
        cur ^= 1;
    }

    // ---- finalize both sub-tiles (row-sum across lg partials, shfl inverse) ----
    float la = lsa, lb = lsb;
    la += __shfl_xor(la, 16); la += __shfl_xor(la, 32);
    lb += __shfl_xor(lb, 16); lb += __shfl_xor(lb, 32);
    float inva_ = 1.0f / la, invb_ = 1.0f / lb;   // valid for q-row lr
    float inva[4], invb[4];
#pragma unroll
    for (int r = 0; r < 4; r++) {
        inva[r] = __shfl(inva_, lg * 4 + r);
        invb[r] = __shfl(invb_, lg * 4 + r);
    }
#pragma unroll
    for (int dt = 0; dt < 4; dt++)
#pragma unroll
        for (int r = 0; r < 4; r++) {
            int qa = q0a + lg * 4 + r;
            int qb = q0b + lg * 4 + r;
            Ob[((size_t)(b * 2048 + qa)) * 1024 + h * 64 + dt * 16 + lr] = f2bf(oa[dt][r] * inva[r]);
            Ob[((size_t)(b * 2048 + qb)) * 1024 + h * 64 + dt * 16 + lr] = f2bf(ob[dt][r] * invb[r]);
        }
}

extern "C" void kernel_launch(void* const* d_in, const int* in_sizes, int n_in,
                              void* d_out, int out_size, void* d_ws, size_t ws_size,
                              hipStream_t stream) {
    const float* x  = (const float*)d_in[0];
    const float* Wq = (const float*)d_in[1];
    const float* Wk = (const float*)d_in[2];
    const float* Wv = (const float*)d_in[3];
    const float* Wo = (const float*)d_in[4];
    float* out = (float*)d_out;

    char* ws = (char*)d_ws;
    short* xb  = (short*)(ws);                 // [4096][1024] bf16       8 MB
    short* Wtb = (short*)(ws + 8388608);       // 4 x [1024 n][1024 k]    8 MB
    short* Qb  = (short*)(ws + 16777216);      // [B,H,S,Dh] (pre-scaled) 8 MB
    short* Kb  = (short*)(ws + 25165824);      // [B,H,S,Dh]              8 MB
    short* Vtb = (short*)(ws + 33554432);      // [B,H,Dh,S]              8 MB
    short* Ob  = (short*)(ws + 41943040);      // [B,S,D] bf16            8 MB

    k_prep<<<8192, 256, 0, stream>>>(x, xb, Wq, Wk, Wv, Wo, Wtb);
    k_gemmQKV<<<dim3(32, 8, 3), 512, 0, stream>>>(xb, Wtb, Qb, Kb, Vtb);
    k_attn<<<512, 256, 0, stream>>>(Qb, Kb, Vtb, Ob);
    k_gemmO<<<dim3(32, 8), 512, 0, stream>>>(Ob, Wtb + 3 * 1048576, out);
}

// Round 17
// 106.778 us; speedup vs baseline: 1.1931x; 1.0003x over previous
//
#include <hip/hip_runtime.h>

typedef __attribute__((ext_vector_type(4))) short short4v;
typedef __attribute__((ext_vector_type(8))) short short8v;
typedef __attribute__((ext_vector_type(4))) float float4v;
typedef __attribute__((ext_vector_type(4))) int int4v;

#define GLD_LDS16(gsrc, ldst)                                                             \
    __builtin_amdgcn_global_load_lds(                                                     \
        (const __attribute__((address_space(1))) void*)(gsrc),                            \
        (__attribute__((address_space(3))) void*)(ldst), 16, 0, 0)

__device__ __forceinline__ short f2bf(float f) {
    unsigned u = __builtin_bit_cast(unsigned, f);
    u += 0x7fffu + ((u >> 16) & 1u);
    return (short)(u >> 16);
}

// ---------------- fused prep: x cvt (blocks 0..4095) + W transpose (4096..8191) ----
__global__ void k_prep(const float* __restrict__ x, short* __restrict__ xb,
                       const float* __restrict__ W0, const float* __restrict__ W1,
                       const float* __restrict__ W2, const float* __restrict__ W3,
                       short* __restrict__ Wt) {
    __shared__ float tile[32][33];
    int bid = blockIdx.x;
    if (bid < 4096) {
        int i = bid * 256 + threadIdx.x;
        float4v v = ((const float4v*)x)[i];
        short4v o;
        o[0] = f2bf(v[0]); o[1] = f2bf(v[1]); o[2] = f2bf(v[2]); o[3] = f2bf(v[3]);
        ((short4v*)xb)[i] = o;
        return;
    }
    int L = bid - 4096;                  // 0..4095
    int z = L >> 10;                     // weight 0..3
    int xy = L & 1023;
    int bx = xy & 31, by = xy >> 5;
    const float* W = z == 0 ? W0 : z == 1 ? W1 : z == 2 ? W2 : W3;
    short* dst = Wt + (size_t)z * 1024 * 1024;
    int x0 = bx * 32, y0 = by * 32;
    int tx = threadIdx.x & 31, ty = threadIdx.x >> 5;   // 32 x 8
#pragma unroll
    for (int j = 0; j < 4; j++) {
        int r = ty + j * 8;
        tile[r][tx] = W[(size_t)(y0 + r) * 1024 + x0 + tx];
    }
    __syncthreads();
#pragma unroll
    for (int j = 0; j < 4; j++) {
        int r = ty + j * 8;
        dst[(size_t)(x0 + r) * 1024 + y0 + tx] = f2bf(tile[tx][r]);
    }
}

// ---------------- merged QKV GEMM: single dispatch, N=3072 (rows 0..3071 of Wtb) ----
// grid (32, 24): which = blockIdx.y>>3 (block-uniform). which<2 -> Q/K head-major;
// which==2 -> V via swapped MFMA operands -> V^T [B,H,Dh,S].
__launch_bounds__(512, 4)
__global__ void k_gemmQKV(const short* __restrict__ A, const short* __restrict__ Wtb,
                          short* __restrict__ Qb, short* __restrict__ Kb,
                          short* __restrict__ Vtb) {
    __shared__ short As[2][128][64];
    __shared__ short Bs[2][128][64];
    int t = threadIdx.x;
    int l = t & 63, w = t >> 6;
    int wm = w >> 2, wn = w & 3;
    int lr = l & 15, lg = l >> 4;
    int m0 = blockIdx.x * 128;
    int nfull = blockIdx.y * 128;            // 0..2944 global weight-row base
    int which = nfull >> 10;                 // 0:Q 1:K 2:V (block-uniform)
    int nb = nfull & 1023;                   // within-weight column base

    int srow = l >> 3;
    int sg = (l & 7) ^ srow;
    const short* Ab0 = A + (size_t)(m0 + w * 8 + srow) * 1024 + sg * 8;
    const short* Ab1 = Ab0 + 64 * 1024;
    const short* Bb0 = Wtb + (size_t)(nfull + w * 8 + srow) * 1024 + sg * 8;
    const short* Bb1 = Bb0 + 64 * 1024;

    float4v acc[4][2] = {};

#define STAGE(bb, k0)                                   \
    do {                                                \
        GLD_LDS16(Ab0 + (k0), &As[bb][w * 8][0]);       \
        GLD_LDS16(Ab1 + (k0), &As[bb][64 + w * 8][0]);  \
        GLD_LDS16(Bb0 + (k0), &Bs[bb][w * 8][0]);       \
        GLD_LDS16(Bb1 + (k0), &Bs[bb][64 + w * 8][0]);  \
    } while (0)

    STAGE(0, 0);
    __syncthreads();
    int cur = 0;

    if (which == 2) {                        // block-uniform branch: V (swapped)
        for (int kt = 0; kt < 16; kt++) {
            if (kt + 1 < 16) STAGE(cur ^ 1, (kt + 1) * 64);
#pragma unroll
            for (int ks = 0; ks < 2; ks++) {
                short8v af[4], bfv[2];
                int hh = ks * 4 + lg;
                int sw = ((hh ^ (lr & 7)) * 8);
#pragma unroll
                for (int fm = 0; fm < 4; fm++)
                    af[fm] = *(const short8v*)&As[cur][wm * 64 + fm * 16 + lr][sw];
#pragma unroll
                for (int fn = 0; fn < 2; fn++)
                    bfv[fn] = *(const short8v*)&Bs[cur][wn * 32 + fn * 16 + lr][sw];
                __builtin_amdgcn_s_setprio(1);
#pragma unroll
                for (int fm = 0; fm < 4; fm++)
#pragma unroll
                    for (int fn = 0; fn < 2; fn++)
                        acc[fm][fn] = __builtin_amdgcn_mfma_f32_16x16x32_bf16(bfv[fn], af[fm], acc[fm][fn], 0, 0, 0);
                __builtin_amdgcn_s_setprio(0);
            }
            __syncthreads();
            cur ^= 1;
        }
    } else {
        for (int kt = 0; kt < 16; kt++) {
            if (kt + 1 < 16) STAGE(cur ^ 1, (kt + 1) * 64);
#pragma unroll
            for (int ks = 0; ks < 2; ks++) {
                short8v af[4], bfv[2];
                int hh = ks * 4 + lg;
                int sw = ((hh ^ (lr & 7)) * 8);
#pragma unroll
                for (int fm = 0; fm < 4; fm++)
                    af[fm] = *(const short8v*)&As[cur][wm * 64 + fm * 16 + lr][sw];
#pragma unroll
                for (int fn = 0; fn < 2; fn++)
                    bfv[fn] = *(const short8v*)&Bs[cur][wn * 32 + fn * 16 + lr][sw];
                __builtin_amdgcn_s_setprio(1);
#pragma unroll
                for (int fm = 0; fm < 4; fm++)
#pragma unroll
                    for (int fn = 0; fn < 2; fn++)
                        acc[fm][fn] = __builtin_amdgcn_mfma_f32_16x16x32_bf16(af[fm], bfv[fn], acc[fm][fn], 0, 0, 0);
                __builtin_amdgcn_s_setprio(0);
            }
            __syncthreads();
            cur ^= 1;
        }
    }
#undef STAGE

    if (which < 2) {
        short* out = (which == 0) ? Qb : Kb;
        float scale = (which == 0) ? 0.125f * 1.44269504088896f : 1.0f;
#pragma unroll
        for (int fm = 0; fm < 4; fm++)
#pragma unroll
            for (int fn = 0; fn < 2; fn++)
#pragma unroll
                for (int r = 0; r < 4; r++) {
                    int m = m0 + wm * 64 + fm * 16 + lg * 4 + r;
                    int n = nb + wn * 32 + fn * 16 + lr;
                    float v = acc[fm][fn][r] * scale;
                    int b = m >> 11, s = m & 2047, h = n >> 6, dh = n & 63;
                    out[(((size_t)(b * 16 + h)) * 2048 + s) * 64 + dh] = f2bf(v);
                }
    } else {
#pragma unroll
        for (int fm = 0; fm < 4; fm++)
#pragma unroll
            for (int fn = 0; fn < 2; fn++)
#pragma unroll
                for (int r = 0; r < 4; r++) {
                    int n = nb + wn * 32 + fn * 16 + lg * 4 + r;
                    int m = m0 + wm * 64 + fm * 16 + lr;
                    int b = m >> 11, s = m & 2047, h = n >> 6, dh = n & 63;
                    Vtb[(((size_t)(b * 16 + h)) * 64 + dh) * 2048 + s] = f2bf(acc[fm][fn][r]);
                }
    }
}

// ---------------- O-projection GEMM (fp32 out) ----------------
__launch_bounds__(512, 4)
__global__ void k_gemmO(const short* __restrict__ A, const short* __restrict__ Bt,
                        float* __restrict__ outF) {
    __shared__ short As[2][128][64];
    __shared__ short Bs[2][128][64];
    int t = threadIdx.x;
    int l = t & 63, w = t >> 6;
    int wm = w >> 2, wn = w & 3;
    int lr = l & 15, lg = l >> 4;
    int m0 = blockIdx.x * 128, n0 = blockIdx.y * 128;

    int srow = l >> 3;
    int sg = (l & 7) ^ srow;
    const short* Ab0 = A + (size_t)(m0 + w * 8 + srow) * 1024 + sg * 8;
    const short* Ab1 = Ab0 + 64 * 1024;
    const short* Bb0 = Bt + (size_t)(n0 + w * 8 + srow) * 1024 + sg * 8;
    const short* Bb1 = Bb0 + 64 * 1024;

    float4v acc[4][2] = {};

#define STAGE(bb, k0)                                   \
    do {                                                \
        GLD_LDS16(Ab0 + (k0), &As[bb][w * 8][0]);       \
        GLD_LDS16(Ab1 + (k0), &As[bb][64 + w * 8][0]);  \
        GLD_LDS16(Bb0 + (k0), &Bs[bb][w * 8][0]);       \
        GLD_LDS16(Bb1 + (k0), &Bs[bb][64 + w * 8][0]);  \
    } while (0)

    STAGE(0, 0);
    __syncthreads();
    int cur = 0;

    for (int kt = 0; kt < 16; kt++) {
        if (kt + 1 < 16) STAGE(cur ^ 1, (kt + 1) * 64);
#pragma unroll
        for (int ks = 0; ks < 2; ks++) {
            short8v af[4], bfv[2];
            int hh = ks * 4 + lg;
            int sw = ((hh ^ (lr & 7)) * 8);
#pragma unroll
            for (int fm = 0; fm < 4; fm++)
                af[fm] = *(const short8v*)&As[cur][wm * 64 + fm * 16 + lr][sw];
#pragma unroll
            for (int fn = 0; fn < 2; fn++)
                bfv[fn] = *(const short8v*)&Bs[cur][wn * 32 + fn * 16 + lr][sw];
            __builtin_amdgcn_s_setprio(1);
#pragma unroll
            for (int fm = 0; fm < 4; fm++)
#pragma unroll
                for (int fn = 0; fn < 2; fn++)
                    acc[fm][fn] = __builtin_amdgcn_mfma_f32_16x16x32_bf16(af[fm], bfv[fn], acc[fm][fn], 0, 0, 0);
            __builtin_amdgcn_s_setprio(0);
        }
        __syncthreads();
        cur ^= 1;
    }
#undef STAGE

#pragma unroll
    for (int fm = 0; fm < 4; fm++)
#pragma unroll
        for (int fn = 0; fn < 2; fn++)
#pragma unroll
            for (int r = 0; r < 4; r++) {
                int m = m0 + wm * 64 + fm * 16 + lg * 4 + r;
                int n = n0 + wn * 32 + fn * 16 + lr;
                outF[(size_t)m * 1024 + n] = acc[fm][fn][r];
            }
}

// ---------------- causal flash attention v15 (unchanged from R15) ----------------
__launch_bounds__(256, 2)
__global__ void k_attn(const short* __restrict__ Qb, const short* __restrict__ Kb,
                       const short* __restrict__ Vtb, short* __restrict__ Ob) {
    __shared__ short K_lds[2][64][64];
    __shared__ short V_lds[2][64][64];
    __shared__ short p_lds[4][2][16][64];
    int t = threadIdx.x;
    int l = t & 63, w = t >> 6;
    int lr = l & 15, lg = l >> 4;

    int L = blockIdx.x;                      // 0..511
    int bh = L & 31;                         // L%8 = bh%8 -> XCD affinity
    int g = L >> 5;                          // 0..15
    int p = (g < 8) ? g : 23 - g;            // heavy first; CU pair sums constant
    int nch = 32 - p;                        // staged chunks (covers hi tile)

    const short* Qp = Qb + (size_t)bh * 2048 * 64;
    const short* Kp = Kb + (size_t)bh * 2048 * 64;
    const short* Vp = Vtb + (size_t)bh * 64 * 2048;

    auto stage = [&](int bb, int kv0) {
#pragma unroll
        for (int i = 0; i < 2; i++) {
            int s = t + i * 256;
            int row = s >> 3, cg = s & 7;
            int cs = (cg ^ (row & 7)) * 8;
            GLD_LDS16(&Kp[(size_t)(kv0 + row) * 64 + cs], (short*)K_lds[bb] + (size_t)s * 8);
            GLD_LDS16(&Vp[(size_t)row * 2048 + kv0 + cs], (short*)V_lds[bb] + (size_t)s * 8);
        }
    };

    stage(0, 0);

    int q0a = (31 - p) * 64 + w * 16;        // sub-tile A rows (hi tile)
    int q0b = p * 64 + w * 16;               // sub-tile B rows (lo tile)
    short8v qf0a = *(const short8v*)&Qp[(size_t)(q0a + lr) * 64 + lg * 8];
    short8v qf1a = *(const short8v*)&Qp[(size_t)(q0a + lr) * 64 + 32 + lg * 8];
    short8v qf0b = *(const short8v*)&Qp[(size_t)(q0b + lr) * 64 + lg * 8];
    short8v qf1b = *(const short8v*)&Qp[(size_t)(q0b + lr) * 64 + 32 + lg * 8];

    float4v oa[4] = {}, ob[4] = {};
    float mra = -3e38f, mrb = -3e38f;        // running max for q = lr (lane-local)
    float lsa = 0.f, lsb = 0.f;              // partial row-sum (this lane's kv share)
    int cur = 0;
    int b = bh >> 4, h = bh & 15;

    // swapped-layout softmax + packed P store (v_cvt_pk_bf16_f32, T12 recipe)
    auto softmax_store = [&](float4v (&s)[4], float& mr, float& ls,
                             float4v (&o)[4], int X) {
        float mx = -3e38f;
#pragma unroll
        for (int t4 = 0; t4 < 4; t4++)
#pragma unroll
            for (int r = 0; r < 4; r++) mx = fmaxf(mx, s[t4][r]);

        if (!__all(mx - mr <= 8.f)) {        // rare: first chunk / big max jump
            float m_ = fmaxf(mx, __shfl_xor(mx, 16));
            m_ = fmaxf(m_, __shfl_xor(m_, 32));
            float mnew = fmaxf(mr, m_);
            float sc = __builtin_amdgcn_exp2f(mr - mnew);
            mr = mnew;
            ls *= sc;
#pragma unroll
            for (int r = 0; r < 4; r++) {
                float scq = __shfl(sc, lg * 4 + r);   // scale for O's q-row 4lg+r
                o[0][r] *= scq; o[1][r] *= scq; o[2][r] *= scq; o[3][r] *= scq;
            }
        }
        int rx = lr & 7;
        int half = (lg & 1) * 4;
#pragma unroll
        for (int t4 = 0; t4 < 4; t4++) {
            float e0 = __builtin_amdgcn_exp2f(s[t4][0] - mr);
            float e1 = __builtin_amdgcn_exp2f(s[t4][1] - mr);
            float e2 = __builtin_amdgcn_exp2f(s[t4][2] - mr);
            float e3 = __builtin_amdgcn_exp2f(s[t4][3] - mr);
            ls += (e0 + e1) + (e2 + e3);
            unsigned lo, hi;
            asm("v_cvt_pk_bf16_f32 %0, %1, %2" : "=v"(lo) : "v"(e0), "v"(e1));
            asm("v_cvt_pk_bf16_f32 %0, %1, %2" : "=v"(hi) : "v"(e2), "v"(e3));
            int grp = (2 * t4 + (lg >> 1)) ^ rx;
            *(unsigned long long*)&p_lds[w][X][lr][grp * 8 + half] =
                (unsigned long long)lo | ((unsigned long long)hi << 32);
        }
    };

    __syncthreads();   // prologue stage drained

    for (int ci = 0; ci < nch; ci++) {
        int kv0 = ci * 64;
        bool dual = (ci <= p);               // block-uniform: B sub-tile active

        if (ci + 1 < nch) stage(cur ^ 1, (ci + 1) * 64);

        const short* Kf = (const short*)K_lds[cur];
        float4v sa[4] = {}, sb[4] = {};
        __builtin_amdgcn_s_setprio(1);
#pragma unroll
        for (int t4 = 0; t4 < 4; t4++) {
            int krow = t4 * 16 + lr;
            int sw = (krow & 7);
            short8v kfa = *(const short8v*)&Kf[krow * 64 + ((lg ^ sw) * 8)];
            short8v kfb = *(const short8v*)&Kf[krow * 64 + (((lg ^ 4) ^ sw) * 8)];
            sa[t4] = __builtin_amdgcn_mfma_f32_16x16x32_bf16(kfa, qf0a, sa[t4], 0, 0, 0);
            sa[t4] = __builtin_amdgcn_mfma_f32_16x16x32_bf16(kfb, qf1a, sa[t4], 0, 0, 0);
            if (dual) {
                sb[t4] = __builtin_amdgcn_mfma_f32_16x16x32_bf16(kfa, qf0b, sb[t4], 0, 0, 0);
                sb[t4] = __builtin_amdgcn_mfma_f32_16x16x32_bf16(kfb, qf1b, sb[t4], 0, 0, 0);
            }
        }
        __builtin_amdgcn_s_setprio(0);

        // swapped layout: lane holds S[kv=kv0+16t4+4lg+r][q=q0+lr]
        if (kv0 + 63 > q0a) {
#pragma unroll
            for (int t4 = 0; t4 < 4; t4++)
#pragma unroll
                for (int r = 0; r < 4; r++)
                    if (kv0 + t4 * 16 + 4 * lg + r > q0a + lr) sa[t4][r] = -3e38f;
        }
        if (dual && kv0 + 63 > q0b) {
#pragma unroll
            for (int t4 = 0; t4 < 4; t4++)
#pragma unroll
                for (int r = 0; r < 4; r++)
                    if (kv0 + t4 * 16 + 4 * lg + r > q0b + lr) sb[t4][r] = -3e38f;
        }

        softmax_store(sa, mra, lsa, oa, 0);
        if (dual) softmax_store(sb, mrb, lsb, ob, 1);

        int prx = lr & 7;
        short8v pa0 = *(const short8v*)&p_lds[w][0][lr][8 * (lg ^ prx)];
        short8v pa1 = *(const short8v*)&p_lds[w][0][lr][8 * ((4 + lg) ^ prx)];
        short8v pb0, pb1;
        if (dual) {
            pb0 = *(const short8v*)&p_lds[w][1][lr][8 * (lg ^ prx)];
            pb1 = *(const short8v*)&p_lds[w][1][lr][8 * ((4 + lg) ^ prx)];
        }

        const short* Vf = (const short*)V_lds[cur];
        __builtin_amdgcn_s_setprio(1);
#pragma unroll
        for (int dt = 0; dt < 4; dt++) {
            int vrow = dt * 16 + lr;
            int sw = (vrow & 7);
            short8v vfa = *(const short8v*)&Vf[vrow * 64 + ((lg ^ sw) * 8)];
            short8v vfb = *(const short8v*)&Vf[vrow * 64 + (((lg ^ 4) ^ sw) * 8)];
            oa[dt] = __builtin_amdgcn_mfma_f32_16x16x32_bf16(pa0, vfa, oa[dt], 0, 0, 0);
            oa[dt] = __builtin_amdgcn_mfma_f32_16x16x32_bf16(pa1, vfb, oa[dt], 0, 0, 0);
            if (dual) {
                ob[dt] = __builtin_amdgcn_mfma_f32_16x16x32_bf16(pb0, vfa, ob[dt], 0, 0, 0);
                ob[dt] = __builtin_amdgcn_mfma_f32_16x16x32_bf16(pb1, vfb, ob[dt], 0, 0, 0);
            }
        }
        __builtin_amdgcn_s_setprio(0);

        __syncthreads();   // buffer flip: all reads of cur done + staging drained
        cur ^= 1;
    }

    // ---- finalize both sub-tiles (row-sum across lg partials, shfl inverse) ----
    float la = lsa, lb = lsb;
    la += __shfl_xor(la, 16); la += __shfl_xor(la, 32);
    lb += __shfl_xor(lb, 16); lb += __shfl_xor(lb, 32);
    float inva_ = 1.0f / la, invb_ = 1.0f / lb;   // valid for q-row lr
    float inva[4], invb[4];
#pragma unroll
    for (int r = 0; r < 4; r++) {
        inva[r] = __shfl(inva_, lg * 4 + r);
        invb[r] = __shfl(invb_, lg * 4 + r);
    }
#pragma unroll
    for (int dt = 0; dt < 4; dt++)
#pragma unroll
        for (int r = 0; r < 4; r++) {
            int qa = q0a + lg * 4 + r;
            int qb = q0b + lg * 4 + r;
            Ob[((size_t)(b * 2048 + qa)) * 1024 + h * 64 + dt * 16 + lr] = f2bf(oa[dt][r] * inva[r]);
            Ob[((size_t)(b * 2048 + qb)) * 1024 + h * 64 + dt * 16 + lr] = f2bf(ob[dt][r] * invb[r]);
        }
}

extern "C" void kernel_launch(void* const* d_in, const int* in_sizes, int n_in,
                              void* d_out, int out_size, void* d_ws, size_t ws_size,
                              hipStream_t stream) {
    const float* x  = (const float*)d_in[0];
    const float* Wq = (const float*)d_in[1];
    const float* Wk = (const float*)d_in[2];
    const float* Wv = (const float*)d_in[3];
    const float* Wo = (const float*)d_in[4];
    float* out = (float*)d_out;

    char* ws = (char*)d_ws;
    short* xb  = (short*)(ws);                 // [4096][1024] bf16       8 MB
    short* Wtb = (short*)(ws + 8388608);       // 4 x [1024 n][1024 k]    8 MB
    short* Qb  = (short*)(ws + 16777216);      // [B,H,S,Dh] (pre-scaled) 8 MB
    short* Kb  = (short*)(ws + 25165824);      // [B,H,S,Dh]              8 MB
    short* Vtb = (short*)(ws + 33554432);      // [B,H,Dh,S]              8 MB
    short* Ob  = (short*)(ws + 41943040);      // [B,S,D] bf16            8 MB

    k_prep<<<8192, 256, 0, stream>>>(x, xb, Wq, Wk, Wv, Wo, Wtb);
    k_gemmQKV<<<dim3(32, 24), 512, 0, stream>>>(xb, Wtb, Qb, Kb, Vtb);
    k_attn<<<512, 256, 0, stream>>>(Qb, Kb, Vtb, Ob);
    k_gemmO<<<dim3(32, 8), 512, 0, stream>>>(Ob, Wtb + 3 * 1048576, out);
}

// Round 18
// 105.352 us; speedup vs baseline: 1.2092x; 1.0135x over previous
//
#include <hip/hip_runtime.h>

typedef __attribute__((ext_vector_type(4))) short short4v;
typedef __attribute__((ext_vector_type(8))) short short8v;
typedef __attribute__((ext_vector_type(4))) float float4v;
typedef __attribute__((ext_vector_type(4))) int int4v;

#define GLD_LDS16(gsrc, ldst)                                                             \
    __builtin_amdgcn_global_load_lds(                                                     \
        (const __attribute__((address_space(1))) void*)(gsrc),                            \
        (__attribute__((address_space(3))) void*)(ldst), 16, 0, 0)

__device__ __forceinline__ short f2bf(float f) {
    unsigned u = __builtin_bit_cast(unsigned, f);
    u += 0x7fffu + ((u >> 16) & 1u);
    return (short)(u >> 16);
}

// ---------------- fused prep: x cvt (blocks 0..4095) + W transpose (4096..8191) ----
__global__ void k_prep(const float* __restrict__ x, short* __restrict__ xb,
                       const float* __restrict__ W0, const float* __restrict__ W1,
                       const float* __restrict__ W2, const float* __restrict__ W3,
                       short* __restrict__ Wt) {
    __shared__ float tile[32][33];
    int bid = blockIdx.x;
    if (bid < 4096) {
        int i = bid * 256 + threadIdx.x;
        float4v v = ((const float4v*)x)[i];
        short4v o;
        o[0] = f2bf(v[0]); o[1] = f2bf(v[1]); o[2] = f2bf(v[2]); o[3] = f2bf(v[3]);
        ((short4v*)xb)[i] = o;
        return;
    }
    int L = bid - 4096;                  // 0..4095
    int z = L >> 10;                     // weight 0..3
    int xy = L & 1023;
    int bx = xy & 31, by = xy >> 5;
    const float* W = z == 0 ? W0 : z == 1 ? W1 : z == 2 ? W2 : W3;
    short* dst = Wt + (size_t)z * 1024 * 1024;
    int x0 = bx * 32, y0 = by * 32;
    int tx = threadIdx.x & 31, ty = threadIdx.x >> 5;   // 32 x 8
#pragma unroll
    for (int j = 0; j < 4; j++) {
        int r = ty + j * 8;
        tile[r][tx] = W[(size_t)(y0 + r) * 1024 + x0 + tx];
    }
    __syncthreads();
#pragma unroll
    for (int j = 0; j < 4; j++) {
        int r = ty + j * 8;
        dst[(size_t)(x0 + r) * 1024 + y0 + tx] = f2bf(tile[tx][r]);
    }
}

// ---------------- merged QKV GEMM: single dispatch, N=3072 (rows 0..3071 of Wtb) ----
__launch_bounds__(512, 4)
__global__ void k_gemmQKV(const short* __restrict__ A, const short* __restrict__ Wtb,
                          short* __restrict__ Qb, short* __restrict__ Kb,
                          short* __restrict__ Vtb) {
    __shared__ short As[2][128][64];
    __shared__ short Bs[2][128][64];
    int t = threadIdx.x;
    int l = t & 63, w = t >> 6;
    int wm = w >> 2, wn = w & 3;
    int lr = l & 15, lg = l >> 4;
    int m0 = blockIdx.x * 128;
    int nfull = blockIdx.y * 128;            // 0..2944 global weight-row base
    int which = nfull >> 10;                 // 0:Q 1:K 2:V (block-uniform)
    int nb = nfull & 1023;                   // within-weight column base

    int srow = l >> 3;
    int sg = (l & 7) ^ srow;
    const short* Ab0 = A + (size_t)(m0 + w * 8 + srow) * 1024 + sg * 8;
    const short* Ab1 = Ab0 + 64 * 1024;
    const short* Bb0 = Wtb + (size_t)(nfull + w * 8 + srow) * 1024 + sg * 8;
    const short* Bb1 = Bb0 + 64 * 1024;

    float4v acc[4][2] = {};

#define STAGE(bb, k0)                                   \
    do {                                                \
        GLD_LDS16(Ab0 + (k0), &As[bb][w * 8][0]);       \
        GLD_LDS16(Ab1 + (k0), &As[bb][64 + w * 8][0]);  \
        GLD_LDS16(Bb0 + (k0), &Bs[bb][w * 8][0]);       \
        GLD_LDS16(Bb1 + (k0), &Bs[bb][64 + w * 8][0]);  \
    } while (0)

    STAGE(0, 0);
    __syncthreads();
    int cur = 0;

    if (which == 2) {                        // block-uniform branch: V (swapped)
        for (int kt = 0; kt < 16; kt++) {
            if (kt + 1 < 16) STAGE(cur ^ 1, (kt + 1) * 64);
#pragma unroll
            for (int ks = 0; ks < 2; ks++) {
                short8v af[4], bfv[2];
                int hh = ks * 4 + lg;
                int sw = ((hh ^ (lr & 7)) * 8);
#pragma unroll
                for (int fm = 0; fm < 4; fm++)
                    af[fm] = *(const short8v*)&As[cur][wm * 64 + fm * 16 + lr][sw];
#pragma unroll
                for (int fn = 0; fn < 2; fn++)
                    bfv[fn] = *(const short8v*)&Bs[cur][wn * 32 + fn * 16 + lr][sw];
                __builtin_amdgcn_s_setprio(1);
#pragma unroll
                for (int fm = 0; fm < 4; fm++)
#pragma unroll
                    for (int fn = 0; fn < 2; fn++)
                        acc[fm][fn] = __builtin_amdgcn_mfma_f32_16x16x32_bf16(bfv[fn], af[fm], acc[fm][fn], 0, 0, 0);
                __builtin_amdgcn_s_setprio(0);
            }
            __syncthreads();
            cur ^= 1;
        }
    } else {
        for (int kt = 0; kt < 16; kt++) {
            if (kt + 1 < 16) STAGE(cur ^ 1, (kt + 1) * 64);
#pragma unroll
            for (int ks = 0; ks < 2; ks++) {
                short8v af[4], bfv[2];
                int hh = ks * 4 + lg;
                int sw = ((hh ^ (lr & 7)) * 8);
#pragma unroll
                for (int fm = 0; fm < 4; fm++)
                    af[fm] = *(const short8v*)&As[cur][wm * 64 + fm * 16 + lr][sw];
#pragma unroll
                for (int fn = 0; fn < 2; fn++)
                    bfv[fn] = *(const short8v*)&Bs[cur][wn * 32 + fn * 16 + lr][sw];
                __builtin_amdgcn_s_setprio(1);
#pragma unroll
                for (int fm = 0; fm < 4; fm++)
#pragma unroll
                    for (int fn = 0; fn < 2; fn++)
                        acc[fm][fn] = __builtin_amdgcn_mfma_f32_16x16x32_bf16(af[fm], bfv[fn], acc[fm][fn], 0, 0, 0);
                __builtin_amdgcn_s_setprio(0);
            }
            __syncthreads();
            cur ^= 1;
        }
    }
#undef STAGE

    if (which < 2) {
        short* out = (which == 0) ? Qb : Kb;
        float scale = (which == 0) ? 0.125f * 1.44269504088896f : 1.0f;
#pragma unroll
        for (int fm = 0; fm < 4; fm++)
#pragma unroll
            for (int fn = 0; fn < 2; fn++)
#pragma unroll
                for (int r = 0; r < 4; r++) {
                    int m = m0 + wm * 64 + fm * 16 + lg * 4 + r;
                    int n = nb + wn * 32 + fn * 16 + lr;
                    float v = acc[fm][fn][r] * scale;
                    int b = m >> 11, s = m & 2047, h = n >> 6, dh = n & 63;
                    out[(((size_t)(b * 16 + h)) * 2048 + s) * 64 + dh] = f2bf(v);
                }
    } else {
#pragma unroll
        for (int fm = 0; fm < 4; fm++)
#pragma unroll
            for (int fn = 0; fn < 2; fn++)
#pragma unroll
                for (int r = 0; r < 4; r++) {
                    int n = nb + wn * 32 + fn * 16 + lg * 4 + r;
                    int m = m0 + wm * 64 + fm * 16 + lr;
                    int b = m >> 11, s = m & 2047, h = n >> 6, dh = n & 63;
                    Vtb[(((size_t)(b * 16 + h)) * 64 + dh) * 2048 + s] = f2bf(acc[fm][fn][r]);
                }
    }
}

// ---------------- O-projection GEMM (fp32 out) ----------------
__launch_bounds__(512, 4)
__global__ void k_gemmO(const short* __restrict__ A, const short* __restrict__ Bt,
                        float* __restrict__ outF) {
    __shared__ short As[2][128][64];
    __shared__ short Bs[2][128][64];
    int t = threadIdx.x;
    int l = t & 63, w = t >> 6;
    int wm = w >> 2, wn = w & 3;
    int lr = l & 15, lg = l >> 4;
    int m0 = blockIdx.x * 128, n0 = blockIdx.y * 128;

    int srow = l >> 3;
    int sg = (l & 7) ^ srow;
    const short* Ab0 = A + (size_t)(m0 + w * 8 + srow) * 1024 + sg * 8;
    const short* Ab1 = Ab0 + 64 * 1024;
    const short* Bb0 = Bt + (size_t)(n0 + w * 8 + srow) * 1024 + sg * 8;
    const short* Bb1 = Bb0 + 64 * 1024;

    float4v acc[4][2] = {};

#define STAGE(bb, k0)                                   \
    do {                                                \
        GLD_LDS16(Ab0 + (k0), &As[bb][w * 8][0]);       \
        GLD_LDS16(Ab1 + (k0), &As[bb][64 + w * 8][0]);  \
        GLD_LDS16(Bb0 + (k0), &Bs[bb][w * 8][0]);       \
        GLD_LDS16(Bb1 + (k0), &Bs[bb][64 + w * 8][0]);  \
    } while (0)

    STAGE(0, 0);
    __syncthreads();
    int cur = 0;

    for (int kt = 0; kt < 16; kt++) {
        if (kt + 1 < 16) STAGE(cur ^ 1, (kt + 1) * 64);
#pragma unroll
        for (int ks = 0; ks < 2; ks++) {
            short8v af[4], bfv[2];
            int hh = ks * 4 + lg;
            int sw = ((hh ^ (lr & 7)) * 8);
#pragma unroll
            for (int fm = 0; fm < 4; fm++)
                af[fm] = *(const short8v*)&As[cur][wm * 64 + fm * 16 + lr][sw];
#pragma unroll
            for (int fn = 0; fn < 2; fn++)
                bfv[fn] = *(const short8v*)&Bs[cur][wn * 32 + fn * 16 + lr][sw];
            __builtin_amdgcn_s_setprio(1);
#pragma unroll
            for (int fm = 0; fm < 4; fm++)
#pragma unroll
                for (int fn = 0; fn < 2; fn++)
                    acc[fm][fn] = __builtin_amdgcn_mfma_f32_16x16x32_bf16(af[fm], bfv[fn], acc[fm][fn], 0, 0, 0);
            __builtin_amdgcn_s_setprio(0);
        }
        __syncthreads();
        cur ^= 1;
    }
#undef STAGE

#pragma unroll
    for (int fm = 0; fm < 4; fm++)
#pragma unroll
        for (int fn = 0; fn < 2; fn++)
#pragma unroll
            for (int r = 0; r < 4; r++) {
                int m = m0 + wm * 64 + fm * 16 + lg * 4 + r;
                int n = n0 + wn * 32 + fn * 16 + lr;
                outF[(size_t)m * 1024 + n] = acc[fm][fn][r];
            }
}

// ---------------- causal flash attention v16: in-register P (no LDS round-trip) ----
// Swapped QK^T leaves lane (lr,lg) holding P[q=lr][kv=16t4+4lg+r]. Using the
// sigma-permuted K-contraction (A slot k=8lg+j <-> kv=16(j>>2)+4lg+(j&3) per
// 32-group), pa0/pa1 are built in-register via v_cvt_pk_bf16_f32 (no cross-lane
// moves, no p_lds). V B-fragments follow the same sigma: two 8B LDS reads at
// cols {4lg, 16+4lg} (+32 for second half), swizzle-adjusted.
__launch_bounds__(256, 2)
__global__ void k_attn(const short* __restrict__ Qb, const short* __restrict__ Kb,
                       const short* __restrict__ Vtb, short* __restrict__ Ob) {
    __shared__ short K_lds[2][64][64];
    __shared__ short V_lds[2][64][64];
    int t = threadIdx.x;
    int l = t & 63, w = t >> 6;
    int lr = l & 15, lg = l >> 4;

    int L = blockIdx.x;                      // 0..511
    int bh = L & 31;                         // L%8 = bh%8 -> XCD affinity
    int g = L >> 5;                          // 0..15
    int p = (g < 8) ? g : 23 - g;            // heavy first; CU pair sums constant
    int nch = 32 - p;                        // staged chunks (covers hi tile)

    const short* Qp = Qb + (size_t)bh * 2048 * 64;
    const short* Kp = Kb + (size_t)bh * 2048 * 64;
    const short* Vp = Vtb + (size_t)bh * 64 * 2048;

    auto stage = [&](int bb, int kv0) {
#pragma unroll
        for (int i = 0; i < 2; i++) {
            int s = t + i * 256;
            int row = s >> 3, cg = s & 7;
            int cs = (cg ^ (row & 7)) * 8;
            GLD_LDS16(&Kp[(size_t)(kv0 + row) * 64 + cs], (short*)K_lds[bb] + (size_t)s * 8);
            GLD_LDS16(&Vp[(size_t)row * 2048 + kv0 + cs], (short*)V_lds[bb] + (size_t)s * 8);
        }
    };

    stage(0, 0);

    int q0a = (31 - p) * 64 + w * 16;        // sub-tile A rows (hi tile)
    int q0b = p * 64 + w * 16;               // sub-tile B rows (lo tile)
    short8v qf0a = *(const short8v*)&Qp[(size_t)(q0a + lr) * 64 + lg * 8];
    short8v qf1a = *(const short8v*)&Qp[(size_t)(q0a + lr) * 64 + 32 + lg * 8];
    short8v qf0b = *(const short8v*)&Qp[(size_t)(q0b + lr) * 64 + lg * 8];
    short8v qf1b = *(const short8v*)&Qp[(size_t)(q0b + lr) * 64 + 32 + lg * 8];

    float4v oa[4] = {}, ob[4] = {};
    float mra = -3e38f, mrb = -3e38f;        // running max for q = lr (lane-local)
    float lsa = 0.f, lsb = 0.f;              // partial row-sum (this lane's kv share)
    int cur = 0;
    int b = bh >> 4, h = bh & 15;
    int g0 = lg >> 1;                        // V b64 16B-group base
    int hb = (lg & 1) * 4;                   // V b64 half offset (shorts)

    // swapped-layout softmax + in-register P pack (sigma order)
    auto softmax_pack = [&](float4v (&s)[4], float& mr, float& ls, float4v (&o)[4],
                            short8v& pa0, short8v& pa1) {
        float mx = -3e38f;
#pragma unroll
        for (int t4 = 0; t4 < 4; t4++)
#pragma unroll
            for (int r = 0; r < 4; r++) mx = fmaxf(mx, s[t4][r]);

        if (!__all(mx - mr <= 8.f)) {        // rare: first chunk / big max jump
            float m_ = fmaxf(mx, __shfl_xor(mx, 16));
            m_ = fmaxf(m_, __shfl_xor(m_, 32));
            float mnew = fmaxf(mr, m_);
            float sc = __builtin_amdgcn_exp2f(mr - mnew);
            mr = mnew;
            ls *= sc;
#pragma unroll
            for (int r = 0; r < 4; r++) {
                float scq = __shfl(sc, lg * 4 + r);   // scale for O's q-row 4lg+r
                o[0][r] *= scq; o[1][r] *= scq; o[2][r] *= scq; o[3][r] *= scq;
            }
        }
        unsigned d[8];
#pragma unroll
        for (int t4 = 0; t4 < 4; t4++) {
            float e0 = __builtin_amdgcn_exp2f(s[t4][0] - mr);
            float e1 = __builtin_amdgcn_exp2f(s[t4][1] - mr);
            float e2 = __builtin_amdgcn_exp2f(s[t4][2] - mr);
            float e3 = __builtin_amdgcn_exp2f(s[t4][3] - mr);
            ls += (e0 + e1) + (e2 + e3);
            asm("v_cvt_pk_bf16_f32 %0, %1, %2" : "=v"(d[2 * t4])     : "v"(e0), "v"(e1));
            asm("v_cvt_pk_bf16_f32 %0, %1, %2" : "=v"(d[2 * t4 + 1]) : "v"(e2), "v"(e3));
        }
        pa0 = __builtin_bit_cast(short8v, int4v{(int)d[0], (int)d[1], (int)d[2], (int)d[3]});
        pa1 = __builtin_bit_cast(short8v, int4v{(int)d[4], (int)d[5], (int)d[6], (int)d[7]});
    };

    __syncthreads();   // prologue stage drained

    for (int ci = 0; ci < nch; ci++) {
        int kv0 = ci * 64;
        bool dual = (ci <= p);               // block-uniform: B sub-tile active

        if (ci + 1 < nch) stage(cur ^ 1, (ci + 1) * 64);

        const short* Kf = (const short*)K_lds[cur];
        float4v sa[4] = {}, sb[4] = {};
        __builtin_amdgcn_s_setprio(1);
#pragma unroll
        for (int t4 = 0; t4 < 4; t4++) {
            int krow = t4 * 16 + lr;
            int sw = (krow & 7);
            short8v kfa = *(const short8v*)&Kf[krow * 64 + ((lg ^ sw) * 8)];
            short8v kfb = *(const short8v*)&Kf[krow * 64 + (((lg ^ 4) ^ sw) * 8)];
            sa[t4] = __builtin_amdgcn_mfma_f32_16x16x32_bf16(kfa, qf0a, sa[t4], 0, 0, 0);
            sa[t4] = __builtin_amdgcn_mfma_f32_16x16x32_bf16(kfb, qf1a, sa[t4], 0, 0, 0);
            if (dual) {
                sb[t4] = __builtin_amdgcn_mfma_f32_16x16x32_bf16(kfa, qf0b, sb[t4], 0, 0, 0);
                sb[t4] = __builtin_amdgcn_mfma_f32_16x16x32_bf16(kfb, qf1b, sb[t4], 0, 0, 0);
            }
        }
        __builtin_amdgcn_s_setprio(0);

        // swapped layout: lane holds S[kv=kv0+16t4+4lg+r][q=q0+lr]
        if (kv0 + 63 > q0a) {
#pragma unroll
            for (int t4 = 0; t4 < 4; t4++)
#pragma unroll
                for (int r = 0; r < 4; r++)
                    if (kv0 + t4 * 16 + 4 * lg + r > q0a + lr) sa[t4][r] = -3e38f;
        }
        if (dual && kv0 + 63 > q0b) {
#pragma unroll
            for (int t4 = 0; t4 < 4; t4++)
#pragma unroll
                for (int r = 0; r < 4; r++)
                    if (kv0 + t4 * 16 + 4 * lg + r > q0b + lr) sb[t4][r] = -3e38f;
        }

        short8v pa0, pa1, pb0, pb1;
        softmax_pack(sa, mra, lsa, oa, pa0, pa1);
        if (dual) softmax_pack(sb, mrb, lsb, ob, pb0, pb1);

        // ---- PV: V B-fragments in sigma order (two b64 reads each) ----
        const short* Vf = (const short*)V_lds[cur];
        __builtin_amdgcn_s_setprio(1);
#pragma unroll
        for (int dt = 0; dt < 4; dt++) {
            int vrow = dt * 16 + lr;
            int sw = (vrow & 7);
            const short* Vr = Vf + vrow * 64;
            short4v a0 = *(const short4v*)&Vr[((g0    ) ^ sw) * 8 + hb];
            short4v a1 = *(const short4v*)&Vr[((g0 + 2) ^ sw) * 8 + hb];
            short4v b0 = *(const short4v*)&Vr[((g0 + 4) ^ sw) * 8 + hb];
            short4v b1 = *(const short4v*)&Vr[((g0 + 6) ^ sw) * 8 + hb];
            short8v vfa, vfb;
            vfa[0] = a0[0]; vfa[1] = a0[1]; vfa[2] = a0[2]; vfa[3] = a0[3];
            vfa[4] = a1[0]; vfa[5] = a1[1]; vfa[6] = a1[2]; vfa[7] = a1[3];
            vfb[0] = b0[0]; vfb[1] = b0[1]; vfb[2] = b0[2]; vfb[3] = b0[3];
            vfb[4] = b1[0]; vfb[5] = b1[1]; vfb[6] = b1[2]; vfb[7] = b1[3];
            oa[dt] = __builtin_amdgcn_mfma_f32_16x16x32_bf16(pa0, vfa, oa[dt], 0, 0, 0);
            oa[dt] = __builtin_amdgcn_mfma_f32_16x16x32_bf16(pa1, vfb, oa[dt], 0, 0, 0);
            if (dual) {
                ob[dt] = __builtin_amdgcn_mfma_f32_16x16x32_bf16(pb0, vfa, ob[dt], 0, 0, 0);
                ob[dt] = __builtin_amdgcn_mfma_f32_16x16x32_bf16(pb1, vfb, ob[dt], 0, 0, 0);
            }
        }
        __builtin_amdgcn_s_setprio(0);

        __syncthreads();   // buffer flip: all reads of cur done + staging drained
        cur ^= 1;
    }

    // ---- finalize both sub-tiles (row-sum across lg partials, shfl inverse) ----
    float la = lsa, lb = lsb;
    la += __shfl_xor(la, 16); la += __shfl_xor(la, 32);
    lb += __shfl_xor(lb, 16); lb += __shfl_xor(lb, 32);
    float inva_ = 1.0f / la, invb_ = 1.0f / lb;   // valid for q-row lr
    float inva[4], invb[4];
#pragma unroll
    for (int r = 0; r < 4; r++) {
        inva[r] = __shfl(inva_, lg * 4 + r);
        invb[r] = __shfl(invb_, lg * 4 + r);
    }
#pragma unroll
    for (int dt = 0; dt < 4; dt++)
#pragma unroll
        for (int r = 0; r < 4; r++) {
            int qa = q0a + lg * 4 + r;
            int qb = q0b + lg * 4 + r;
            Ob[((size_t)(b * 2048 + qa)) * 1024 + h * 64 + dt * 16 + lr] = f2bf(oa[dt][r] * inva[r]);
            Ob[((size_t)(b * 2048 + qb)) * 1024 + h * 64 + dt * 16 + lr] = f2bf(ob[dt][r] * invb[r]);
        }
}

extern "C" void kernel_launch(void* const* d_in, const int* in_sizes, int n_in,
                              void* d_out, int out_size, void* d_ws, size_t ws_size,
                              hipStream_t stream) {
    const float* x  = (const float*)d_in[0];
    const float* Wq = (const float*)d_in[1];
    const float* Wk = (const float*)d_in[2];
    const float* Wv = (const float*)d_in[3];
    const float* Wo = (const float*)d_in[4];
    float* out = (float*)d_out;

    char* ws = (char*)d_ws;
    short* xb  = (short*)(ws);                 // [4096][1024] bf16       8 MB
    short* Wtb = (short*)(ws + 8388608);       // 4 x [1024 n][1024 k]    8 MB
    short* Qb  = (short*)(ws + 16777216);      // [B,H,S,Dh] (pre-scaled) 8 MB
    short* Kb  = (short*)(ws + 25165824);      // [B,H,S,Dh]              8 MB
    short* Vtb = (short*)(ws + 33554432);      // [B,H,Dh,S]              8 MB
    short* Ob  = (short*)(ws + 41943040);      // [B,S,D] bf16            8 MB

    k_prep<<<8192, 256, 0, stream>>>(x, xb, Wq, Wk, Wv, Wo, Wtb);
    k_gemmQKV<<<dim3(32, 24), 512, 0, stream>>>(xb, Wtb, Qb, Kb, Vtb);
    k_attn<<<512, 256, 0, stream>>>(Qb, Kb, Vtb, Ob);
    k_gemmO<<<dim3(32, 8), 512, 0, stream>>>(Ob, Wtb + 3 * 1048576, out);
}